// Round 1
// baseline (260.235 us; speedup 1.0000x reference)
//
#include <hip/hip_runtime.h>
#include <math.h>

// Problem constants
#define NB   2
#define CIN  128
#define CMID 64
#define HW   64
#define CENC 100   // (SCALE*KUP)^2 = 100
#define OCS  112   // padded oc stride for transposed enc weights (16B-aligned rows)

// Workspace layout (floats)
#define OFF_WCOMB 0                         // [25][128][64]  combined 5x5 weights, oc fastest
#define SZ_WCOMB  (25*128*64)
#define OFF_BCOMB (OFF_WCOMB + SZ_WCOMB)    // [64] combined bias
#define OFF_WENC  (OFF_BCOMB + 64)          // [9][64][OCS] transposed enc weights
#define SZ_WENC   (9*64*OCS)
#define OFF_W     (OFF_WENC + SZ_WENC)      // [2][64][64][64] mid feature map (in-place updated)
#define SZ_W      (NB*CMID*HW*HW)
#define OFF_ENC   (OFF_W + SZ_W)            // [2][100][64][64] encoder output
#define SZ_ENC    (NB*CENC*HW*HW)
#define OFF_AVG   (OFF_ENC + SZ_ENC)        // [2][64]
#define OFF_GATE  (OFF_AVG + NB*CMID)       // [2][64]

// ---------------------------------------------------------------------------
// Kernel 1: weight prep. wcomb[k][ci][oc] = w5 + embedded w3; bcomb = b3+b5;
// wenc_t[k][ci][oc] (oc stride OCS) = wenc transposed.
// ---------------------------------------------------------------------------
__global__ __launch_bounds__(256) void prep_kernel(
    const float* __restrict__ w3, const float* __restrict__ b3,
    const float* __restrict__ w5, const float* __restrict__ b5,
    const float* __restrict__ wenc, float* __restrict__ ws) {
  int idx = blockIdx.x * 256 + threadIdx.x;
  if (idx < 25 * 128 * 64) {
    int oc = idx & 63;
    int t  = idx >> 6;
    int ci = t & 127;
    int k  = t >> 7;            // 0..24
    int ky = k / 5, kx = k % 5;
    float v = w5[(oc * 128 + ci) * 25 + k];
    if (ky >= 1 && ky <= 3 && kx >= 1 && kx <= 3)
      v += w3[(oc * 128 + ci) * 9 + (ky - 1) * 3 + (kx - 1)];
    ws[OFF_WCOMB + idx] = v;
  }
  if (idx < 64) ws[OFF_BCOMB + idx] = b3[idx] + b5[idx];
  if (idx < 9 * 64 * 100) {
    int oc = idx % 100;
    int t  = idx / 100;
    int ci = t & 63;
    int k  = t >> 6;            // 0..8
    ws[OFF_WENC + (k * 64 + ci) * OCS + oc] = wenc[(oc * 64 + ci) * 9 + k];
  }
}

// ---------------------------------------------------------------------------
// Kernel 2: combined 5x5 conv  X(2,128,64,64) -> W(2,64,64,64)
// Block: 256 thr = 4 waves; each wave: 64 pixels (8x8 tile) x 4 output chans.
// Input tile staged in LDS in 2 ci-chunks of 64; weights via scalar loads.
// ---------------------------------------------------------------------------
__global__ __launch_bounds__(256) void convw_kernel(const float* __restrict__ X,
                                                    float* __restrict__ ws) {
  const int tid = threadIdx.x;
  const int z = blockIdx.z;
  const int b = z >> 2, ocg = z & 3;
  const int tx0 = blockIdx.x * 8, ty0 = blockIdx.y * 8;
  __shared__ float tile[64 * 144];  // [ci][12*12]

  int oc0 = ocg * 16 + (tid >> 6) * 4;
  oc0 = __builtin_amdgcn_readfirstlane(oc0);
  const int lane = tid & 63;
  const int py = lane >> 3, px = lane & 7;

  const float* bc = ws + OFF_BCOMB;
  float4 acc = {bc[oc0], bc[oc0 + 1], bc[oc0 + 2], bc[oc0 + 3]};
  const float* wc = ws + OFF_WCOMB + oc0;

  for (int ch = 0; ch < 2; ++ch) {
    if (ch) __syncthreads();
    // stage 64 ci x 12x12 halo tile
    for (int i = tid; i < 768; i += 256) {
      int ci = i / 12, yy = i % 12;
      int gy = ty0 - 2 + yy;
      const float* src = X + (((b * 128 + ch * 64 + ci) * 64 + gy) * 64) + (tx0 - 2);
      float* dst = &tile[ci * 144 + yy * 12];
      bool rowok = (gy >= 0 && gy < 64);
#pragma unroll
      for (int xx = 0; xx < 12; ++xx) {
        int gx = tx0 - 2 + xx;
        dst[xx] = (rowok && gx >= 0 && gx < 64) ? src[xx] : 0.f;
      }
    }
    __syncthreads();
    for (int ci = 0; ci < 64; ++ci) {
      const float* trow = &tile[ci * 144 + py * 12 + px];
      const float* wrow = wc + (ch * 64 + ci) * 64;   // + k*8192 per tap
#pragma unroll
      for (int ky = 0; ky < 5; ++ky) {
#pragma unroll
        for (int kx = 0; kx < 5; ++kx) {
          float v = trow[ky * 12 + kx];
          float4 wv = *(const float4*)(wrow + (ky * 5 + kx) * 8192);
          acc.x = fmaf(wv.x, v, acc.x);
          acc.y = fmaf(wv.y, v, acc.y);
          acc.z = fmaf(wv.z, v, acc.z);
          acc.w = fmaf(wv.w, v, acc.w);
        }
      }
    }
  }
  int gy = ty0 + py, gx = tx0 + px;
  float* op = ws + OFF_W + ((b * 64 + oc0) * 64 + gy) * 64 + gx;
  op[0] = acc.x;
  op[4096] = acc.y;
  op[8192] = acc.z;
  op[12288] = acc.w;
}

// ---------------------------------------------------------------------------
// Kernel 3: per-(b,c) plane mean of W
// ---------------------------------------------------------------------------
__global__ __launch_bounds__(256) void mean_kernel(float* __restrict__ ws) {
  int bc = blockIdx.x;  // 0..127
  const float* p = ws + OFF_W + bc * 4096;
  float s = 0.f;
  for (int i = threadIdx.x; i < 4096; i += 256) s += p[i];
  __shared__ float red[256];
  red[threadIdx.x] = s;
  __syncthreads();
  for (int off = 128; off > 0; off >>= 1) {
    if (threadIdx.x < off) red[threadIdx.x] += red[threadIdx.x + off];
    __syncthreads();
  }
  if (threadIdx.x == 0) ws[OFF_AVG + bc] = red[0] * (1.f / 4096.f);
}

// ---------------------------------------------------------------------------
// Kernel 4: SE gate: sigmoid(wa2 @ (wa1 @ avg + ba1) + ba2)   (no ReLU in ref)
// ---------------------------------------------------------------------------
__global__ __launch_bounds__(64) void gate_kernel(
    const float* __restrict__ wa1, const float* __restrict__ ba1,
    const float* __restrict__ wa2, const float* __restrict__ ba2,
    float* __restrict__ ws) {
  int b = blockIdx.x;
  int t = threadIdx.x;  // 0..63
  __shared__ float av[64];
  __shared__ float tl[8];
  av[t] = ws[OFF_AVG + b * 64 + t];
  __syncthreads();
  if (t < 8) {
    float s = ba1[t];
    for (int i = 0; i < 64; ++i) s += wa1[t * 64 + i] * av[i];
    tl[t] = s;
  }
  __syncthreads();
  float s = ba2[t];
  for (int j = 0; j < 8; ++j) s += wa2[t * 8 + j] * tl[j];
  ws[OFF_GATE + b * 64 + t] = 1.f / (1.f + expf(-s));
}

// ---------------------------------------------------------------------------
// Kernel 5: depthwise 3x3 edge conv + gate apply, in-place on W.
// One block per (b,c) plane (staged fully in LDS first -> in-place safe).
// ---------------------------------------------------------------------------
__global__ __launch_bounds__(256) void edge_kernel(const float* __restrict__ wedge,
                                                   float* __restrict__ ws) {
  int bc = blockIdx.x;
  int c = bc & 63;
  float* plane = ws + OFF_W + bc * 4096;
  __shared__ float t[66 * 66];
  for (int i = threadIdx.x; i < 66 * 66; i += 256) {
    int yy = i / 66, xx = i % 66;
    int gy = yy - 1, gx = xx - 1;
    t[i] = (gy >= 0 && gy < 64 && gx >= 0 && gx < 64) ? plane[gy * 64 + gx] : 0.f;
  }
  __syncthreads();
  float g = ws[OFF_GATE + bc];
  float wk[9];
#pragma unroll
  for (int k = 0; k < 9; ++k) wk[k] = wedge[c * 9 + k];
  for (int p = threadIdx.x; p < 4096; p += 256) {
    int y = p >> 6, x = p & 63;
    float e = 0.f;
#pragma unroll
    for (int ky = 0; ky < 3; ++ky)
#pragma unroll
      for (int kx = 0; kx < 3; ++kx)
        e = fmaf(wk[ky * 3 + kx], t[(y + ky) * 66 + x + kx], e);
    plane[p] = t[(y + 1) * 66 + x + 1] * g + e;
  }
}

// ---------------------------------------------------------------------------
// Kernel 6: encoder 3x3 conv  W(2,64,64,64) -> ENC(2,100,64,64)
// Same structure as convw; oc groups of 16, last group partially masked.
// ---------------------------------------------------------------------------
__global__ __launch_bounds__(256) void enc_kernel(float* __restrict__ ws) {
  const int tid = threadIdx.x;
  const int z = blockIdx.z;
  const int b = z / 7, ocg = z % 7;
  const int tx0 = blockIdx.x * 8, ty0 = blockIdx.y * 8;
  __shared__ float tile[64 * 100];  // [ci][10*10]
  for (int i = tid; i < 640; i += 256) {
    int ci = i / 10, yy = i % 10;
    int gy = ty0 - 1 + yy;
    const float* src = ws + OFF_W + ((b * 64 + ci) * 64 + gy) * 64 + (tx0 - 1);
    float* dst = &tile[ci * 100 + yy * 10];
    bool rowok = (gy >= 0 && gy < 64);
#pragma unroll
    for (int xx = 0; xx < 10; ++xx) {
      int gx = tx0 - 1 + xx;
      dst[xx] = (rowok && gx >= 0 && gx < 64) ? src[xx] : 0.f;
    }
  }
  __syncthreads();
  int oc0 = ocg * 16 + (tid >> 6) * 4;
  oc0 = __builtin_amdgcn_readfirstlane(oc0);
  if (oc0 >= 100) return;
  const int lane = tid & 63;
  const int py = lane >> 3, px = lane & 7;
  float4 acc = {0.f, 0.f, 0.f, 0.f};
  const float* wt = ws + OFF_WENC + oc0;
  for (int ci = 0; ci < 64; ++ci) {
    const float* trow = &tile[ci * 100 + py * 10 + px];
#pragma unroll
    for (int ky = 0; ky < 3; ++ky) {
#pragma unroll
      for (int kx = 0; kx < 3; ++kx) {
        float v = trow[ky * 10 + kx];
        float4 wv = *(const float4*)(wt + ((ky * 3 + kx) * 64 + ci) * OCS);
        acc.x = fmaf(wv.x, v, acc.x);
        acc.y = fmaf(wv.y, v, acc.y);
        acc.z = fmaf(wv.z, v, acc.z);
        acc.w = fmaf(wv.w, v, acc.w);
      }
    }
  }
  int gy = ty0 + py, gx = tx0 + px;
  float* op = ws + OFF_ENC + ((b * 100 + oc0) * 64 + gy) * 64 + gx;
  op[0] = acc.x;
  op[4096] = acc.y;
  op[8192] = acc.z;
  op[12288] = acc.w;
}

// ---------------------------------------------------------------------------
// Kernel 7: CARAFE. Per low-res pixel: 4 softmaxes over 25 enc logits, then
// out[b,c,2h+sy,2w+sx] = sum_k sm[sub][k] * X[b,c,h+ki-2,w+kj-2].
// Block: 8x4 low-res tile; 256 thr = 32 pix x 8 channel-slots.
// X neighborhood staged in LDS (2 chunks of 64 ch), padded strides vs conflicts.
// ---------------------------------------------------------------------------
__global__ __launch_bounds__(256) void carafe_kernel(const float* __restrict__ X,
                                                     const float* __restrict__ ws,
                                                     float* __restrict__ out) {
  const int tid = threadIdx.x;
  const int b = blockIdx.z;
  const int h0 = blockIdx.y * 8, w0 = blockIdx.x * 4;
  __shared__ __attribute__((aligned(16))) float smw[32 * 104];  // [pix][k*4+sub], stride 104
  __shared__ float xt[6240];  // chunk of 64 ci: addr = c*97 + (c>>3)*4 + r*8 + cc

  // softmax weights (threads 0..127: pix x sub)
  if (tid < 128) {
    int pix = tid & 31, sub = tid >> 5;
    int h = h0 + (pix >> 2), w = w0 + (pix & 3);
    const float* enc = ws + OFF_ENC + ((b * 100 + sub) * 64 + h) * 64 + w;
    float l[25];
    float m = -1e30f;
#pragma unroll
    for (int k = 0; k < 25; ++k) {
      l[k] = enc[k * 4 * 4096];
      m = fmaxf(m, l[k]);
    }
    float s = 0.f;
#pragma unroll
    for (int k = 0; k < 25; ++k) {
      l[k] = __expf(l[k] - m);
      s += l[k];
    }
    float inv = 1.f / s;
#pragma unroll
    for (int k = 0; k < 25; ++k) smw[pix * 104 + k * 4 + sub] = l[k] * inv;
  }

  const int slot = tid >> 5, pix = tid & 31;
  const int ph = pix >> 2, pw = pix & 3;

  for (int ch = 0; ch < 2; ++ch) {
    if (ch) __syncthreads();
    // stage X chunk: 64 ci x 12 rows x 8 cols
    for (int i = tid; i < 768; i += 256) {
      int ci = i / 12, r = i % 12;
      int gh = h0 - 2 + r;
      const float* src = X + (((b * 128 + ch * 64 + ci) * 64 + gh) * 64) + (w0 - 2);
      float* dst = &xt[ci * 97 + (ci >> 3) * 4 + r * 8];
      bool rowok = (gh >= 0 && gh < 64);
#pragma unroll
      for (int cc = 0; cc < 8; ++cc) {
        int gw = w0 - 2 + cc;
        dst[cc] = (rowok && gw >= 0 && gw < 64) ? src[cc] : 0.f;
      }
    }
    __syncthreads();

    float acc[4][8];
#pragma unroll
    for (int s4 = 0; s4 < 4; ++s4)
#pragma unroll
      for (int j = 0; j < 8; ++j) acc[s4][j] = 0.f;

    const float* xbase = &xt[slot * 8 * 97 + slot * 4];
    const float* wbase = &smw[pix * 104];
#pragma unroll
    for (int ki = 0; ki < 5; ++ki) {
#pragma unroll
      for (int kj = 0; kj < 5; ++kj) {
        float4 wv = *(const float4*)(wbase + (ki * 5 + kj) * 4);
        const float* xp = xbase + (ph + ki) * 8 + (pw + kj);
#pragma unroll
        for (int j = 0; j < 8; ++j) {
          float xv = xp[j * 97];
          acc[0][j] = fmaf(wv.x, xv, acc[0][j]);
          acc[1][j] = fmaf(wv.y, xv, acc[1][j]);
          acc[2][j] = fmaf(wv.z, xv, acc[2][j]);
          acc[3][j] = fmaf(wv.w, xv, acc[3][j]);
        }
      }
    }
    int y0 = 2 * (h0 + ph), x0 = 2 * (w0 + pw);
#pragma unroll
    for (int j = 0; j < 8; ++j) {
      int c = ch * 64 + slot * 8 + j;
      float* op = out + ((b * 128 + c) * 128 + y0) * 128 + x0;
      float2 v0 = {acc[0][j], acc[1][j]};  // sy=0: sx=0,1
      float2 v1 = {acc[2][j], acc[3][j]};  // sy=1
      *(float2*)op = v0;
      *(float2*)(op + 128) = v1;
    }
  }
}

// ---------------------------------------------------------------------------
extern "C" void kernel_launch(void* const* d_in, const int* in_sizes, int n_in,
                              void* d_out, int out_size, void* d_ws, size_t ws_size,
                              hipStream_t stream) {
  const float* X     = (const float*)d_in[0];
  const float* w3    = (const float*)d_in[1];
  const float* b3    = (const float*)d_in[2];
  const float* w5    = (const float*)d_in[3];
  const float* b5    = (const float*)d_in[4];
  const float* wa1   = (const float*)d_in[5];
  const float* ba1   = (const float*)d_in[6];
  const float* wa2   = (const float*)d_in[7];
  const float* ba2   = (const float*)d_in[8];
  const float* wedge = (const float*)d_in[9];
  const float* wenc  = (const float*)d_in[10];
  float* ws  = (float*)d_ws;   // needs ~6.46 MB
  float* out = (float*)d_out;

  prep_kernel<<<800, 256, 0, stream>>>(w3, b3, w5, b5, wenc, ws);
  convw_kernel<<<dim3(8, 8, 8), 256, 0, stream>>>(X, ws);
  mean_kernel<<<128, 256, 0, stream>>>(ws);
  gate_kernel<<<2, 64, 0, stream>>>(wa1, ba1, wa2, ba2, ws);
  edge_kernel<<<128, 256, 0, stream>>>(wedge, ws);
  enc_kernel<<<dim3(8, 8, 14), 256, 0, stream>>>(ws);
  carafe_kernel<<<dim3(16, 8, 2), 256, 0, stream>>>(X, ws, out);
}

// Round 2
// 174.097 us; speedup vs baseline: 1.4948x; 1.4948x over previous
//
#include <hip/hip_runtime.h>
#include <math.h>

// Workspace layout (float offsets)
#define OFF_WCOMB 0                           // [25][128][64]
#define OFF_BCOMB 204800                      // [64]
#define OFF_WENC  204864                      // [9][64][112] (oc>=100 zeroed)
#define OFF_XPAD  269376                      // [2][128][68][72], data at (y+2,x+2)
#define OFF_WPAD  1522752                     // [2][64][66][68],  data at (y+1,x+1)
#define OFF_ENC   2097216                     // [2][100][64][64]
#define OFF_AVG   2916416                     // [128]
#define OFF_GATE  2916544                     // [128]
// total 2916672 floats = 11.67 MB

// ---------------------------------------------------------------------------
// prep: combined 5x5 weights, enc-weight transpose (zero-padded to 112),
// bias sum, Xpad fill, Wpad zero, AVG zero.
// ---------------------------------------------------------------------------
__global__ __launch_bounds__(256) void prep_kernel(
    const float* __restrict__ X,
    const float* __restrict__ w3, const float* __restrict__ b3,
    const float* __restrict__ w5, const float* __restrict__ b5,
    const float* __restrict__ wenc, float* __restrict__ ws) {
  int idx = blockIdx.x * 256 + threadIdx.x;
  // Xpad: [bc][68][72]
  if (idx < 2 * 128 * 68 * 72) {
    int xx = idx % 72;
    int t = idx / 72;
    int yy = t % 68;
    int bc = t / 68;
    int y = yy - 2, x = xx - 2;
    float v = (y >= 0 && y < 64 && x >= 0 && x < 64) ? X[bc * 4096 + y * 64 + x] : 0.f;
    ws[OFF_XPAD + idx] = v;
  }
  if (idx < 2 * 64 * 66 * 68) ws[OFF_WPAD + idx] = 0.f;
  if (idx < 25 * 128 * 64) {
    int oc = idx & 63;
    int t = idx >> 6;
    int ci = t & 127;
    int k = t >> 7;
    int ky = k / 5, kx = k % 5;
    float v = w5[(oc * 128 + ci) * 25 + k];
    if (ky >= 1 && ky <= 3 && kx >= 1 && kx <= 3)
      v += w3[(oc * 128 + ci) * 9 + (ky - 1) * 3 + (kx - 1)];
    ws[OFF_WCOMB + idx] = v;
  }
  if (idx < 9 * 64 * 112) {
    int oc = idx % 112;
    int t = idx / 112;
    int ci = t & 63;
    int k = t >> 6;
    ws[OFF_WENC + idx] = (oc < 100) ? wenc[(oc * 64 + ci) * 9 + k] : 0.f;
  }
  if (idx < 64) ws[OFF_BCOMB + idx] = b3[idx] + b5[idx];
  if (idx < 128) ws[OFF_AVG + idx] = 0.f;
}

// ---------------------------------------------------------------------------
// convw: combined 5x5 conv Xpad -> Wpad, fused plane-mean (atomicAdd to AVG).
// Block: 4 waves, 8x8 pixel tile, 4 oc; waves split ci (8 each per 32-chunk).
// Grid (8,8,32): z = b*16 + ocg.
// ---------------------------------------------------------------------------
__global__ __launch_bounds__(256) void convw_kernel(float* __restrict__ ws) {
  const int tid = threadIdx.x;
  const int z = blockIdx.z;
  const int b = z >> 4, ocg = z & 15;
  const int oc0 = ocg * 4;
  const int tx0 = blockIdx.x * 8, ty0 = blockIdx.y * 8;
  __shared__ __attribute__((aligned(16))) float tile[32 * 144];  // [ci][12*12]

  const int w8 = __builtin_amdgcn_readfirstlane((tid >> 6) * 8);
  const int lane = tid & 63;
  const int py = lane >> 3, px = lane & 7;

  float4 acc = {0.f, 0.f, 0.f, 0.f};
  const float* xpad = ws + OFF_XPAD;
  const float* wc = ws + OFF_WCOMB + oc0;

  for (int c = 0; c < 4; ++c) {
    if (c) __syncthreads();
    // stage 32 ci x 12 rows x 12 cols (3 float4 segs), branch-free
    for (int u = tid; u < 1152; u += 256) {
      int ci = u / 36;
      int rem = u - ci * 36;
      int r = rem / 3, s = rem - r * 3;
      const float4* src = (const float4*)(xpad +
          ((size_t)(b * 128 + c * 32 + ci) * 68 + ty0 + r) * 72 + tx0 + s * 4);
      *(float4*)(&tile[ci * 144 + r * 12 + s * 4]) = *src;
    }
    __syncthreads();
    for (int i = 0; i < 8; ++i) {
      const float* trow = &tile[(w8 + i) * 144 + py * 12 + px];
      const float* wrow = wc + ((c * 32 + w8 + i) * 64);  // + tap*8192
#pragma unroll
      for (int ky = 0; ky < 5; ++ky) {
#pragma unroll
        for (int kx = 0; kx < 5; ++kx) {
          float v = trow[ky * 12 + kx];
          float4 wv = *(const float4*)(wrow + (ky * 5 + kx) * 8192);
          acc.x = fmaf(wv.x, v, acc.x);
          acc.y = fmaf(wv.y, v, acc.y);
          acc.z = fmaf(wv.z, v, acc.z);
          acc.w = fmaf(wv.w, v, acc.w);
        }
      }
    }
  }
  // cross-wave reduce via LDS [16][64]
  __syncthreads();
  float* red = tile;
  const int w = w8 >> 3;
  red[(w * 4 + 0) * 64 + lane] = acc.x;
  red[(w * 4 + 1) * 64 + lane] = acc.y;
  red[(w * 4 + 2) * 64 + lane] = acc.z;
  red[(w * 4 + 3) * 64 + lane] = acc.w;
  __syncthreads();
  if (tid < 64) {
    const float* bc = ws + OFF_BCOMB + oc0;
    float v[4];
#pragma unroll
    for (int j = 0; j < 4; ++j)
      v[j] = red[j * 64 + tid] + red[(4 + j) * 64 + tid] +
             red[(8 + j) * 64 + tid] + red[(12 + j) * 64 + tid] + bc[j];
    int gy = ty0 + (tid >> 3) + 1, gx = tx0 + (tid & 7) + 1;
    float* op = ws + OFF_WPAD + ((size_t)(b * 64 + oc0) * 66 + gy) * 68 + gx;
#pragma unroll
    for (int j = 0; j < 4; ++j) op[j * 66 * 68] = v[j];
    // fused mean: wave-reduce the 64 pixel values, atomicAdd per oc
#pragma unroll
    for (int j = 0; j < 4; ++j) {
      float s = v[j];
#pragma unroll
      for (int off = 32; off > 0; off >>= 1) s += __shfl_down(s, off);
      if (tid == 0) atomicAdd(&ws[OFF_AVG + b * 64 + oc0 + j], s * (1.f / 4096.f));
    }
  }
}

// ---------------------------------------------------------------------------
// gate: sigmoid(wa2 @ (wa1 @ avg + ba1) + ba2)
// ---------------------------------------------------------------------------
__global__ __launch_bounds__(64) void gate_kernel(
    const float* __restrict__ wa1, const float* __restrict__ ba1,
    const float* __restrict__ wa2, const float* __restrict__ ba2,
    float* __restrict__ ws) {
  int b = blockIdx.x;
  int t = threadIdx.x;
  __shared__ float av[64];
  __shared__ float tl[8];
  av[t] = ws[OFF_AVG + b * 64 + t];
  __syncthreads();
  if (t < 8) {
    float s = ba1[t];
    for (int i = 0; i < 64; ++i) s += wa1[t * 64 + i] * av[i];
    tl[t] = s;
  }
  __syncthreads();
  float s = ba2[t];
#pragma unroll
  for (int j = 0; j < 8; ++j) s += wa2[t * 8 + j] * tl[j];
  ws[OFF_GATE + b * 64 + t] = 1.f / (1.f + expf(-s));
}

// ---------------------------------------------------------------------------
// edge: depthwise 3x3 + gate, in-place on Wpad (full plane staged first).
// ---------------------------------------------------------------------------
__global__ __launch_bounds__(256) void edge_kernel(const float* __restrict__ wedge,
                                                   float* __restrict__ ws) {
  int bc = blockIdx.x;
  int c = bc & 63;
  float* plane = ws + OFF_WPAD + (size_t)bc * 66 * 68;
  __shared__ __attribute__((aligned(16))) float t[66 * 68];
  for (int u = threadIdx.x; u < 66 * 68 / 4; u += 256)
    *(float4*)(&t[u * 4]) = *(const float4*)(plane + u * 4);
  __syncthreads();
  float g = ws[OFF_GATE + bc];
  float wk[9];
#pragma unroll
  for (int k = 0; k < 9; ++k) wk[k] = wedge[c * 9 + k];
  for (int p = threadIdx.x; p < 4096; p += 256) {
    int y = p >> 6, x = p & 63;
    float e = 0.f;
#pragma unroll
    for (int ky = 0; ky < 3; ++ky)
#pragma unroll
      for (int kx = 0; kx < 3; ++kx)
        e = fmaf(wk[ky * 3 + kx], t[(y + ky) * 68 + x + kx], e);
    plane[(y + 1) * 68 + x + 1] = t[(y + 1) * 68 + x + 1] * g + e;
  }
}

// ---------------------------------------------------------------------------
// enc: 3x3 conv Wpad -> ENC. Block: 4 waves, 8x8 tile, 8 oc; waves split ci
// (16 each). Grid (8,8,26): z = b*13 + ocg, oc0 = ocg*8 (mask oc>=100).
// ---------------------------------------------------------------------------
__global__ __launch_bounds__(256) void enc_kernel(float* __restrict__ ws) {
  const int tid = threadIdx.x;
  const int z = blockIdx.z;
  const int b = z / 13, ocg = z % 13;
  const int oc0 = ocg * 8;
  const int tx0 = blockIdx.x * 8, ty0 = blockIdx.y * 8;
  __shared__ __attribute__((aligned(16))) float tile[64 * 120];  // [ci][10*12]

  // stage 64 ci x 10 rows x 12 cols
  for (int u = tid; u < 1920; u += 256) {
    int ci = u / 30;
    int rem = u - ci * 30;
    int r = rem / 3, s = rem - r * 3;
    const float4* src = (const float4*)(ws + OFF_WPAD +
        ((size_t)(b * 64 + ci) * 66 + ty0 + r) * 68 + tx0 + s * 4);
    *(float4*)(&tile[ci * 120 + r * 12 + s * 4]) = *src;
  }
  __syncthreads();

  const int w16 = __builtin_amdgcn_readfirstlane((tid >> 6) * 16);
  const int lane = tid & 63;
  const int py = lane >> 3, px = lane & 7;
  float a0[4] = {0, 0, 0, 0}, a1[4] = {0, 0, 0, 0};
  const float* wt = ws + OFF_WENC + oc0;
  for (int i = 0; i < 16; ++i) {
    int cl = w16 + i;
    const float* trow = &tile[cl * 120 + py * 12 + px];
    const float* wr = wt + cl * 112;  // + tap*7168
#pragma unroll
    for (int ky = 0; ky < 3; ++ky) {
#pragma unroll
      for (int kx = 0; kx < 3; ++kx) {
        float v = trow[ky * 12 + kx];
        const float* wp = wr + (ky * 3 + kx) * 7168;
        float4 w0 = *(const float4*)(wp);
        float4 w1 = *(const float4*)(wp + 4);
        a0[0] = fmaf(w0.x, v, a0[0]);
        a0[1] = fmaf(w0.y, v, a0[1]);
        a0[2] = fmaf(w0.z, v, a0[2]);
        a0[3] = fmaf(w0.w, v, a0[3]);
        a1[0] = fmaf(w1.x, v, a1[0]);
        a1[1] = fmaf(w1.y, v, a1[1]);
        a1[2] = fmaf(w1.z, v, a1[2]);
        a1[3] = fmaf(w1.w, v, a1[3]);
      }
    }
  }
  __syncthreads();
  float* red = tile;  // [32][64]
  const int w = w16 >> 4;
#pragma unroll
  for (int j = 0; j < 4; ++j) {
    red[(w * 8 + j) * 64 + lane] = a0[j];
    red[(w * 8 + 4 + j) * 64 + lane] = a1[j];
  }
  __syncthreads();
  if (tid < 64) {
    int gy = ty0 + (tid >> 3), gx = tx0 + (tid & 7);
#pragma unroll
    for (int j = 0; j < 8; ++j) {
      int oc = oc0 + j;
      if (oc < 100) {
        float s = red[j * 64 + tid] + red[(8 + j) * 64 + tid] +
                  red[(16 + j) * 64 + tid] + red[(24 + j) * 64 + tid];
        ws[OFF_ENC + ((size_t)(b * 100 + oc) * 64 + gy) * 64 + gx] = s;
      }
    }
  }
}

// ---------------------------------------------------------------------------
// carafe: per low-res pixel 4 softmaxes over 25 taps, then weighted gather.
// Grid (16,8,8): z = b*4 + cq (ci quarter). Block: 8x4 pixel tile, 32 ch.
// 256 thr = 32 pix x 8 slots x 4 ch.
// ---------------------------------------------------------------------------
__global__ __launch_bounds__(256) void carafe_kernel(const float* __restrict__ ws,
                                                     float* __restrict__ out) {
  const int tid = threadIdx.x;
  const int z = blockIdx.z;
  const int b = z >> 2, cq = z & 3;
  const int h0 = blockIdx.y * 8, w0 = blockIdx.x * 4;
  __shared__ __attribute__((aligned(16))) float smw[3300];  // [sub][25][33]
  __shared__ __attribute__((aligned(16))) float xt[3224];   // ci*100+(ci>>2)*4+r*8+cc

  // softmax weights
  if (tid < 128) {
    int pix = tid & 31, sub = tid >> 5;
    int h = h0 + (pix >> 2), w = w0 + (pix & 3);
    const float* enc = ws + OFF_ENC + ((size_t)(b * 100 + sub) * 64 + h) * 64 + w;
    float l[25];
    float m = -1e30f;
#pragma unroll
    for (int k = 0; k < 25; ++k) {
      l[k] = enc[k * 16384];
      m = fmaxf(m, l[k]);
    }
    float s = 0.f;
#pragma unroll
    for (int k = 0; k < 25; ++k) {
      l[k] = __expf(l[k] - m);
      s += l[k];
    }
    float inv = 1.f / s;
#pragma unroll
    for (int k = 0; k < 25; ++k) smw[(sub * 25 + k) * 33 + pix] = l[k] * inv;
  }
  // stage 32 ci x 12 rows x 8 cols of Xpad
  for (int u = tid; u < 768; u += 256) {
    int ci = u / 24;
    int rem = u - ci * 24;
    int r = rem >> 1, s = rem & 1;
    const float4* src = (const float4*)(ws + OFF_XPAD +
        ((size_t)(b * 128 + cq * 32 + ci) * 68 + h0 + r) * 72 + w0 + s * 4);
    *(float4*)(&xt[ci * 100 + (ci >> 2) * 4 + r * 8 + s * 4]) = *src;
  }
  __syncthreads();

  const int slot = tid >> 5, pix = tid & 31;
  const int ph = pix >> 2, pw = pix & 3;
  const float* xbase = &xt[slot * 404];

  float acc[4][4];
#pragma unroll
  for (int s = 0; s < 4; ++s)
#pragma unroll
    for (int j = 0; j < 4; ++j) acc[s][j] = 0.f;

#pragma unroll
  for (int ki = 0; ki < 5; ++ki) {
#pragma unroll
    for (int kj = 0; kj < 5; ++kj) {
      int tap = ki * 5 + kj;
      float wv[4];
#pragma unroll
      for (int s = 0; s < 4; ++s) wv[s] = smw[(s * 25 + tap) * 33 + pix];
      int off = (ph + ki) * 8 + (pw + kj);
#pragma unroll
      for (int j = 0; j < 4; ++j) {
        float xv = xbase[j * 100 + off];
        acc[0][j] = fmaf(wv[0], xv, acc[0][j]);
        acc[1][j] = fmaf(wv[1], xv, acc[1][j]);
        acc[2][j] = fmaf(wv[2], xv, acc[2][j]);
        acc[3][j] = fmaf(wv[3], xv, acc[3][j]);
      }
    }
  }
  int y0 = 2 * (h0 + ph), x0 = 2 * (w0 + pw);
#pragma unroll
  for (int j = 0; j < 4; ++j) {
    int c = cq * 32 + slot * 4 + j;
    float* op = out + ((size_t)(b * 128 + c) * 128 + y0) * 128 + x0;
    float2 v0 = {acc[0][j], acc[1][j]};
    float2 v1 = {acc[2][j], acc[3][j]};
    *(float2*)op = v0;
    *(float2*)(op + 128) = v1;
  }
}

// ---------------------------------------------------------------------------
extern "C" void kernel_launch(void* const* d_in, const int* in_sizes, int n_in,
                              void* d_out, int out_size, void* d_ws, size_t ws_size,
                              hipStream_t stream) {
  const float* X     = (const float*)d_in[0];
  const float* w3    = (const float*)d_in[1];
  const float* b3    = (const float*)d_in[2];
  const float* w5    = (const float*)d_in[3];
  const float* b5    = (const float*)d_in[4];
  const float* wa1   = (const float*)d_in[5];
  const float* ba1   = (const float*)d_in[6];
  const float* wa2   = (const float*)d_in[7];
  const float* ba2   = (const float*)d_in[8];
  const float* wedge = (const float*)d_in[9];
  const float* wenc  = (const float*)d_in[10];
  float* ws  = (float*)d_ws;   // ~11.7 MB
  float* out = (float*)d_out;

  prep_kernel<<<4896, 256, 0, stream>>>(X, w3, b3, w5, b5, wenc, ws);
  convw_kernel<<<dim3(8, 8, 32), 256, 0, stream>>>(ws);
  gate_kernel<<<2, 64, 0, stream>>>(wa1, ba1, wa2, ba2, ws);
  edge_kernel<<<128, 256, 0, stream>>>(wedge, ws);
  enc_kernel<<<dim3(8, 8, 26), 256, 0, stream>>>(ws);
  carafe_kernel<<<dim3(16, 8, 8), 256, 0, stream>>>(ws, out);
}

// Round 3
// 133.479 us; speedup vs baseline: 1.9496x; 1.3043x over previous
//
#include <hip/hip_runtime.h>
#include <math.h>

// Workspace layout (float offsets)
#define OFF_WCOMB 0                           // [8 ocg][128 ci][25 tap][8 oc]
#define OFF_BCOMB 204800                      // [64]
#define OFF_WENC  204864                      // [13 ocg][64 ci][9 tap][8 oc] (oc>=100 zero)
#define OFF_XPAD  264768                      // [2][128][68][72], data at (y+2,x+2)
#define OFF_WPAD  1518144                     // [2][64][66][68],  data at (y+1,x+1)
#define OFF_ENC   2092608                     // [2][100][64][64]
#define OFF_AVG   2911808                     // [128]
#define OFF_GATE  2911936                     // [128]
// total 2912064 floats = 11.65 MB

// ---------------------------------------------------------------------------
// prep: combined 5x5 weights (streaming layout), enc weights (streaming
// layout), bias sum, Xpad fill, Wpad zero, AVG zero.
// ---------------------------------------------------------------------------
__global__ __launch_bounds__(256) void prep_kernel(
    const float* __restrict__ X,
    const float* __restrict__ w3, const float* __restrict__ b3,
    const float* __restrict__ w5, const float* __restrict__ b5,
    const float* __restrict__ wenc, float* __restrict__ ws) {
  int idx = blockIdx.x * 256 + threadIdx.x;
  // Xpad: [bc][68][72]
  if (idx < 2 * 128 * 68 * 72) {
    int xx = idx % 72;
    int t = idx / 72;
    int yy = t % 68;
    int bc = t / 68;
    int y = yy - 2, x = xx - 2;
    float v = (y >= 0 && y < 64 && x >= 0 && x < 64) ? X[bc * 4096 + y * 64 + x] : 0.f;
    ws[OFF_XPAD + idx] = v;
  }
  if (idx < 2 * 64 * 66 * 68) ws[OFF_WPAD + idx] = 0.f;
  // wcomb: [(ocg*128+ci)*25+tap]*8+j
  if (idx < 204800) {
    int j = idx & 7;
    int t = idx >> 3;
    int tap = t % 25;
    int t2 = t / 25;
    int ci = t2 & 127;
    int ocg = t2 >> 7;
    int oc = ocg * 8 + j;
    int ky = tap / 5, kx = tap % 5;
    float v = w5[(oc * 128 + ci) * 25 + tap];
    if (ky >= 1 && ky <= 3 && kx >= 1 && kx <= 3)
      v += w3[(oc * 128 + ci) * 9 + (ky - 1) * 3 + (kx - 1)];
    ws[OFF_WCOMB + idx] = v;
  }
  // wenc_t: [(ocg*64+ci)*9+tap]*8+j
  if (idx < 59904) {
    int j = idx & 7;
    int t = idx >> 3;
    int tap = t % 9;
    int t2 = t / 9;
    int ci = t2 & 63;
    int ocg = t2 >> 6;
    int oc = ocg * 8 + j;
    ws[OFF_WENC + idx] = (oc < 100) ? wenc[(oc * 64 + ci) * 9 + tap] : 0.f;
  }
  if (idx < 64) ws[OFF_BCOMB + idx] = b3[idx] + b5[idx];
  if (idx < 128) ws[OFF_AVG + idx] = 0.f;
}

// ---------------------------------------------------------------------------
// convw: combined 5x5 conv Xpad -> Wpad (+fused mean). Block: 4 waves, 8x8
// pixel tile, 8 oc; waves split ci. Weights: contiguous 800B scalar stream
// per ci. Grid (8,8,16): z = b*8 + ocg.
// ---------------------------------------------------------------------------
__global__ __launch_bounds__(256) void convw_kernel(float* __restrict__ ws) {
  const int tid = threadIdx.x;
  const int z = blockIdx.z;
  const int b = z >> 3, ocg = z & 7;
  const int oc0 = ocg * 8;
  const int tx0 = blockIdx.x * 8, ty0 = blockIdx.y * 8;
  __shared__ __attribute__((aligned(16))) float tile[32 * 144];  // [ci][12*12]

  const int w8 = __builtin_amdgcn_readfirstlane((tid >> 6) * 8);
  const int lane = tid & 63;
  const int py = lane >> 3, px = lane & 7;

  float acc[8] = {0, 0, 0, 0, 0, 0, 0, 0};
  const float* xpad = ws + OFF_XPAD;
  const float* wbase = ws + OFF_WCOMB + ocg * 25600;  // 128*200

  for (int c = 0; c < 4; ++c) {
    if (c) __syncthreads();
    for (int u = tid; u < 1152; u += 256) {
      int ci = u / 36;
      int rem = u - ci * 36;
      int r = rem / 3, s = rem - r * 3;
      const float4* src = (const float4*)(xpad +
          ((size_t)(b * 128 + c * 32 + ci) * 68 + ty0 + r) * 72 + tx0 + s * 4);
      *(float4*)(&tile[ci * 144 + r * 12 + s * 4]) = *src;
    }
    __syncthreads();
    for (int i = 0; i < 8; ++i) {
      const float* trow = &tile[(w8 + i) * 144 + py * 12 + px];
      const float* wp = wbase + (c * 32 + w8 + i) * 200;
#pragma unroll
      for (int t = 0; t < 25; ++t) {
        float v = trow[(t / 5) * 12 + (t % 5)];
        float4 wa = *(const float4*)(wp + t * 8);
        float4 wb = *(const float4*)(wp + t * 8 + 4);
        acc[0] = fmaf(wa.x, v, acc[0]);
        acc[1] = fmaf(wa.y, v, acc[1]);
        acc[2] = fmaf(wa.z, v, acc[2]);
        acc[3] = fmaf(wa.w, v, acc[3]);
        acc[4] = fmaf(wb.x, v, acc[4]);
        acc[5] = fmaf(wb.y, v, acc[5]);
        acc[6] = fmaf(wb.z, v, acc[6]);
        acc[7] = fmaf(wb.w, v, acc[7]);
      }
    }
  }
  // cross-wave reduce via LDS [32][64]
  __syncthreads();
  float* red = tile;
  const int w = w8 >> 3;
#pragma unroll
  for (int j = 0; j < 8; ++j) red[(w * 8 + j) * 64 + lane] = acc[j];
  __syncthreads();
  if (tid < 64) {
    const float* bc = ws + OFF_BCOMB + oc0;
    float v[8];
#pragma unroll
    for (int j = 0; j < 8; ++j)
      v[j] = red[j * 64 + tid] + red[(8 + j) * 64 + tid] +
             red[(16 + j) * 64 + tid] + red[(24 + j) * 64 + tid] + bc[j];
    int gy = ty0 + (tid >> 3) + 1, gx = tx0 + (tid & 7) + 1;
    float* op = ws + OFF_WPAD + ((size_t)(b * 64 + oc0) * 66 + gy) * 68 + gx;
#pragma unroll
    for (int j = 0; j < 8; ++j) op[j * 66 * 68] = v[j];
#pragma unroll
    for (int j = 0; j < 8; ++j) {
      float s = v[j];
#pragma unroll
      for (int off = 32; off > 0; off >>= 1) s += __shfl_down(s, off);
      if (tid == 0) atomicAdd(&ws[OFF_AVG + b * 64 + oc0 + j], s * (1.f / 4096.f));
    }
  }
}

// ---------------------------------------------------------------------------
// gate: sigmoid(wa2 @ (wa1 @ avg + ba1) + ba2)
// ---------------------------------------------------------------------------
__global__ __launch_bounds__(64) void gate_kernel(
    const float* __restrict__ wa1, const float* __restrict__ ba1,
    const float* __restrict__ wa2, const float* __restrict__ ba2,
    float* __restrict__ ws) {
  int b = blockIdx.x;
  int t = threadIdx.x;
  __shared__ float av[64];
  __shared__ float tl[8];
  av[t] = ws[OFF_AVG + b * 64 + t];
  __syncthreads();
  if (t < 8) {
    float s = ba1[t];
    for (int i = 0; i < 64; ++i) s += wa1[t * 64 + i] * av[i];
    tl[t] = s;
  }
  __syncthreads();
  float s = ba2[t];
#pragma unroll
  for (int j = 0; j < 8; ++j) s += wa2[t * 8 + j] * tl[j];
  ws[OFF_GATE + b * 64 + t] = 1.f / (1.f + expf(-s));
}

// ---------------------------------------------------------------------------
// edge: depthwise 3x3 + gate, in-place on Wpad (full plane staged first).
// ---------------------------------------------------------------------------
__global__ __launch_bounds__(256) void edge_kernel(const float* __restrict__ wedge,
                                                   float* __restrict__ ws) {
  int bc = blockIdx.x;
  int c = bc & 63;
  float* plane = ws + OFF_WPAD + (size_t)bc * 66 * 68;
  __shared__ __attribute__((aligned(16))) float t[66 * 68];
  for (int u = threadIdx.x; u < 66 * 68 / 4; u += 256)
    *(float4*)(&t[u * 4]) = *(const float4*)(plane + u * 4);
  __syncthreads();
  float g = ws[OFF_GATE + bc];
  float wk[9];
#pragma unroll
  for (int k = 0; k < 9; ++k) wk[k] = wedge[c * 9 + k];
  for (int p = threadIdx.x; p < 4096; p += 256) {
    int y = p >> 6, x = p & 63;
    float e = 0.f;
#pragma unroll
    for (int ky = 0; ky < 3; ++ky)
#pragma unroll
      for (int kx = 0; kx < 3; ++kx)
        e = fmaf(wk[ky * 3 + kx], t[(y + ky) * 68 + x + kx], e);
    plane[(y + 1) * 68 + x + 1] = t[(y + 1) * 68 + x + 1] * g + e;
  }
}

// ---------------------------------------------------------------------------
// enc: 3x3 conv Wpad -> ENC. Block: 4 waves, 8x8 tile, 8 oc; waves split ci
// (16 each). Contiguous 288B weight stream per ci. Grid (8,8,26).
// ---------------------------------------------------------------------------
__global__ __launch_bounds__(256) void enc_kernel(float* __restrict__ ws) {
  const int tid = threadIdx.x;
  const int z = blockIdx.z;
  const int b = z / 13, ocg = z % 13;
  const int oc0 = ocg * 8;
  const int tx0 = blockIdx.x * 8, ty0 = blockIdx.y * 8;
  __shared__ __attribute__((aligned(16))) float tile[64 * 120];  // [ci][10*12]

  for (int u = tid; u < 1920; u += 256) {
    int ci = u / 30;
    int rem = u - ci * 30;
    int r = rem / 3, s = rem - r * 3;
    const float4* src = (const float4*)(ws + OFF_WPAD +
        ((size_t)(b * 64 + ci) * 66 + ty0 + r) * 68 + tx0 + s * 4);
    *(float4*)(&tile[ci * 120 + r * 12 + s * 4]) = *src;
  }
  __syncthreads();

  const int w16 = __builtin_amdgcn_readfirstlane((tid >> 6) * 16);
  const int lane = tid & 63;
  const int py = lane >> 3, px = lane & 7;
  float acc[8] = {0, 0, 0, 0, 0, 0, 0, 0};
  const float* we = ws + OFF_WENC + ocg * 4608;  // 64*72

  for (int i = 0; i < 16; ++i) {
    int ci = w16 + i;
    const float* trow = &tile[ci * 120 + py * 12 + px];
    const float* wp = we + ci * 72;
#pragma unroll
    for (int t = 0; t < 9; ++t) {
      float v = trow[(t / 3) * 12 + (t % 3)];
      float4 wa = *(const float4*)(wp + t * 8);
      float4 wb = *(const float4*)(wp + t * 8 + 4);
      acc[0] = fmaf(wa.x, v, acc[0]);
      acc[1] = fmaf(wa.y, v, acc[1]);
      acc[2] = fmaf(wa.z, v, acc[2]);
      acc[3] = fmaf(wa.w, v, acc[3]);
      acc[4] = fmaf(wb.x, v, acc[4]);
      acc[5] = fmaf(wb.y, v, acc[5]);
      acc[6] = fmaf(wb.z, v, acc[6]);
      acc[7] = fmaf(wb.w, v, acc[7]);
    }
  }
  __syncthreads();
  float* red = tile;  // [32][64]
  const int w = w16 >> 4;
#pragma unroll
  for (int j = 0; j < 8; ++j) red[(w * 8 + j) * 64 + lane] = acc[j];
  __syncthreads();
  if (tid < 64) {
    int gy = ty0 + (tid >> 3), gx = tx0 + (tid & 7);
#pragma unroll
    for (int j = 0; j < 8; ++j) {
      int oc = oc0 + j;
      if (oc < 100) {
        float s = red[j * 64 + tid] + red[(8 + j) * 64 + tid] +
                  red[(16 + j) * 64 + tid] + red[(24 + j) * 64 + tid];
        ws[OFF_ENC + ((size_t)(b * 100 + oc) * 64 + gy) * 64 + gx] = s;
      }
    }
  }
}

// ---------------------------------------------------------------------------
// carafe: per low-res pixel 4 softmaxes over 25 taps, then weighted gather.
// Grid (16,8,8): z = b*4 + cq. Block: 8x4 pixel tile, 32 ch.
// ---------------------------------------------------------------------------
__global__ __launch_bounds__(256) void carafe_kernel(const float* __restrict__ ws,
                                                     float* __restrict__ out) {
  const int tid = threadIdx.x;
  const int z = blockIdx.z;
  const int b = z >> 2, cq = z & 3;
  const int h0 = blockIdx.y * 8, w0 = blockIdx.x * 4;
  __shared__ __attribute__((aligned(16))) float smw[3300];  // [sub][25][33]
  __shared__ __attribute__((aligned(16))) float xt[3224];   // ci*100+(ci>>2)*4+r*8+cc

  if (tid < 128) {
    int pix = tid & 31, sub = tid >> 5;
    int h = h0 + (pix >> 2), w = w0 + (pix & 3);
    const float* enc = ws + OFF_ENC + ((size_t)(b * 100 + sub) * 64 + h) * 64 + w;
    float l[25];
    float m = -1e30f;
#pragma unroll
    for (int k = 0; k < 25; ++k) {
      l[k] = enc[k * 16384];
      m = fmaxf(m, l[k]);
    }
    float s = 0.f;
#pragma unroll
    for (int k = 0; k < 25; ++k) {
      l[k] = __expf(l[k] - m);
      s += l[k];
    }
    float inv = 1.f / s;
#pragma unroll
    for (int k = 0; k < 25; ++k) smw[(sub * 25 + k) * 33 + pix] = l[k] * inv;
  }
  for (int u = tid; u < 768; u += 256) {
    int ci = u / 24;
    int rem = u - ci * 24;
    int r = rem >> 1, s = rem & 1;
    const float4* src = (const float4*)(ws + OFF_XPAD +
        ((size_t)(b * 128 + cq * 32 + ci) * 68 + h0 + r) * 72 + w0 + s * 4);
    *(float4*)(&xt[ci * 100 + (ci >> 2) * 4 + r * 8 + s * 4]) = *src;
  }
  __syncthreads();

  const int slot = tid >> 5, pix = tid & 31;
  const int ph = pix >> 2, pw = pix & 3;
  const float* xbase = &xt[slot * 404];

  float acc[4][4];
#pragma unroll
  for (int s = 0; s < 4; ++s)
#pragma unroll
    for (int j = 0; j < 4; ++j) acc[s][j] = 0.f;

#pragma unroll
  for (int ki = 0; ki < 5; ++ki) {
#pragma unroll
    for (int kj = 0; kj < 5; ++kj) {
      int tap = ki * 5 + kj;
      float wv[4];
#pragma unroll
      for (int s = 0; s < 4; ++s) wv[s] = smw[(s * 25 + tap) * 33 + pix];
      int off = (ph + ki) * 8 + (pw + kj);
#pragma unroll
      for (int j = 0; j < 4; ++j) {
        float xv = xbase[j * 100 + off];
        acc[0][j] = fmaf(wv[0], xv, acc[0][j]);
        acc[1][j] = fmaf(wv[1], xv, acc[1][j]);
        acc[2][j] = fmaf(wv[2], xv, acc[2][j]);
        acc[3][j] = fmaf(wv[3], xv, acc[3][j]);
      }
    }
  }
  int y0 = 2 * (h0 + ph), x0 = 2 * (w0 + pw);
#pragma unroll
  for (int j = 0; j < 4; ++j) {
    int c = cq * 32 + slot * 4 + j;
    float* op = out + ((size_t)(b * 128 + c) * 128 + y0) * 128 + x0;
    float2 v0 = {acc[0][j], acc[1][j]};
    float2 v1 = {acc[2][j], acc[3][j]};
    *(float2*)op = v0;
    *(float2*)(op + 128) = v1;
  }
}

// ---------------------------------------------------------------------------
extern "C" void kernel_launch(void* const* d_in, const int* in_sizes, int n_in,
                              void* d_out, int out_size, void* d_ws, size_t ws_size,
                              hipStream_t stream) {
  const float* X     = (const float*)d_in[0];
  const float* w3    = (const float*)d_in[1];
  const float* b3    = (const float*)d_in[2];
  const float* w5    = (const float*)d_in[3];
  const float* b5    = (const float*)d_in[4];
  const float* wa1   = (const float*)d_in[5];
  const float* ba1   = (const float*)d_in[6];
  const float* wa2   = (const float*)d_in[7];
  const float* ba2   = (const float*)d_in[8];
  const float* wedge = (const float*)d_in[9];
  const float* wenc  = (const float*)d_in[10];
  float* ws  = (float*)d_ws;   // ~11.65 MB
  float* out = (float*)d_out;

  prep_kernel<<<4896, 256, 0, stream>>>(X, w3, b3, w5, b5, wenc, ws);
  convw_kernel<<<dim3(8, 8, 16), 256, 0, stream>>>(ws);
  gate_kernel<<<2, 64, 0, stream>>>(wa1, ba1, wa2, ba2, ws);
  edge_kernel<<<128, 256, 0, stream>>>(wedge, ws);
  enc_kernel<<<dim3(8, 8, 26), 256, 0, stream>>>(ws);
  carafe_kernel<<<dim3(16, 8, 8), 256, 0, stream>>>(ws, out);
}

// Round 4
// 87.770 us; speedup vs baseline: 2.9650x; 1.5208x over previous
//
#include <hip/hip_runtime.h>
#include <math.h>

typedef __attribute__((ext_vector_type(4))) _Float16 f16x4;
typedef __attribute__((ext_vector_type(4))) float f32x4;

// Workspace byte offsets
#define XPAD4_B 0            // [2][32 g][68 y][72 x][4 ci] f16 (data at y+2,x+2)
#define WFC_B   2506752      // convw B-frags [25 t][8 cc][4 ntg][64 l][4] f16
#define WFE_B   2916352      // enc  B-frags [9 t][4 cc][7 nt][64 l][4] f16
#define WPAD4_B 3045376      // [2][16 g][66 y][68 x][4] f16 (data at y+1,x+1)
#define WFEAT_B 4194304      // [2][4096 pix][64 oc] f32
#define ENC_B   6291456      // [2][4096 pix][112 oc] f32
#define BCOMB_B 9961472      // [64] f32
#define AVG_B   9961728      // [128] f32
#define GATE_B  9962240      // [128] f32
// total ~9.96 MB

// ---------------------------------------------------------------------------
// prep: Xpad4 (f16 channel-last-4), MFMA B-fragment packs, bias, zeros.
// ---------------------------------------------------------------------------
__global__ __launch_bounds__(256) void prep_kernel(
    const float* __restrict__ X,
    const float* __restrict__ w3, const float* __restrict__ b3,
    const float* __restrict__ w5, const float* __restrict__ b5,
    const float* __restrict__ wenc, char* __restrict__ wsb) {
  int idx = blockIdx.x * 256 + threadIdx.x;
  // Xpad4: 2*32*68*72 = 313344 units of 4 f16
  if (idx < 313344) {
    int x = idx % 72;
    int t = idx / 72;
    int y = t % 68;
    int t2 = t / 68;
    int g = t2 & 31, b = t2 >> 5;
    int yy = y - 2, xx = x - 2;
    bool ok = (yy >= 0 && yy < 64 && xx >= 0 && xx < 64);
    f16x4 h;
#pragma unroll
    for (int j = 0; j < 4; ++j) {
      float v = ok ? X[((b * 128 + g * 4 + j) << 12) + yy * 64 + xx] : 0.f;
      h[j] = (_Float16)v;
    }
    *((f16x4*)(wsb + XPAD4_B) + idx) = h;
  }
  // convw frags: 25*8*4*64 = 51200 units
  if (idx < 51200) {
    int l = idx & 63;
    int t2 = idx >> 6;
    int ntg = t2 & 3;
    int t3 = t2 >> 2;
    int cc = t3 & 7;
    int t = t3 >> 3;  // tap 0..24
    int ky = t / 5, kx = t % 5;
    int oc = ntg * 16 + (l & 15);
    int ci0 = cc * 16 + (l >> 4) * 4;
    f16x4 h;
#pragma unroll
    for (int i = 0; i < 4; ++i) {
      int ci = ci0 + i;
      float v = w5[(oc * 128 + ci) * 25 + t];
      if (ky >= 1 && ky <= 3 && kx >= 1 && kx <= 3)
        v += w3[(oc * 128 + ci) * 9 + (ky - 1) * 3 + (kx - 1)];
      h[i] = (_Float16)v;
    }
    *((f16x4*)(wsb + WFC_B) + idx) = h;
  }
  // enc frags: 9*4*7*64 = 16128 units
  if (idx < 16128) {
    int l = idx & 63;
    int t2 = idx >> 6;
    int nt = t2 % 7;
    int t3 = t2 / 7;
    int cc = t3 & 3;
    int t = t3 >> 2;  // tap 0..8
    int oc = nt * 16 + (l & 15);
    int ci0 = cc * 16 + (l >> 4) * 4;
    f16x4 h;
#pragma unroll
    for (int i = 0; i < 4; ++i) {
      float v = (oc < 100) ? wenc[(oc * 64 + ci0 + i) * 9 + t] : 0.f;
      h[i] = (_Float16)v;
    }
    *((f16x4*)(wsb + WFE_B) + idx) = h;
  }
  // Wpad4 zero: 2*16*66*68 = 143616 units
  if (idx < 143616) {
    f16x4 z = {(_Float16)0.f, (_Float16)0.f, (_Float16)0.f, (_Float16)0.f};
    *((f16x4*)(wsb + WPAD4_B) + idx) = z;
  }
  if (idx < 64) ((float*)(wsb + BCOMB_B))[idx] = b3[idx] + b5[idx];
  if (idx < 128) ((float*)(wsb + AVG_B))[idx] = 0.f;
}

// ---------------------------------------------------------------------------
// convw MFMA: 5x5 conv via 16x16x16 f16 MFMA. Grid (8,8,4): z = b*2 + oh.
// Block 256 thr = 4 waves; wave w owns pixels 16w..16w+15 (M), 32 oc (2 nt).
// LDS: X tile [32 g][12 r][12 c][4 ci] f16, g-stride 592 f16 (pad 16).
// ---------------------------------------------------------------------------
__global__ __launch_bounds__(256) void convw_kernel(
    const _Float16* __restrict__ xpad4, const f16x4* __restrict__ wfc,
    const float* __restrict__ bcomb, float* __restrict__ wfeat) {
  __shared__ _Float16 xs[32 * 592];
  const int tid = threadIdx.x;
  const int z = blockIdx.z;
  const int b = z >> 1, oh = z & 1;
  const int tx0 = blockIdx.x * 8, ty0 = blockIdx.y * 8;

  // stage: 32 g x 12 r x 12 col-units (b64 each)
  for (int u = tid; u < 4608; u += 256) {
    int g = u / 144;
    int rem = u - g * 144;
    int r = rem / 12, c = rem - r * 12;
    f16x4 v = *(const f16x4*)&xpad4[(((b * 32 + g) * 68 + ty0 + r) * 72 + tx0 + c) * 4];
    *(f16x4*)&xs[g * 592 + r * 48 + c * 4] = v;
  }
  __syncthreads();

  const int w = tid >> 6, l = tid & 63;
  const int lm = l & 15, lg = l >> 4;
  const int p = 16 * w + lm;                  // pixel for A-frag
  const int abase = (p >> 3) * 48 + (p & 7) * 4;
  const int lgoff = lg * 592;

  f32x4 acc0 = {0.f, 0.f, 0.f, 0.f}, acc1 = {0.f, 0.f, 0.f, 0.f};

  for (int dy = 0; dy < 5; ++dy) {
    for (int dx = 0; dx < 5; ++dx) {
      const int t = dy * 5 + dx;
      const int toff = abase + dy * 48 + dx * 4;
      const f16x4* wt = wfc + (t * 32 + oh * 2) * 64 + l;
#pragma unroll
      for (int cc = 0; cc < 8; ++cc) {
        f16x4 a = *(const f16x4*)&xs[cc * 2368 + lgoff + toff];
        f16x4 b0 = wt[cc * 256];
        f16x4 b1 = wt[cc * 256 + 64];
        acc0 = __builtin_amdgcn_mfma_f32_16x16x16f16(a, b0, acc0, 0, 0, 0);
        acc1 = __builtin_amdgcn_mfma_f32_16x16x16f16(a, b1, acc1, 0, 0, 0);
      }
    }
  }
  // store: D[m = 4*lg + r][n = lm]; pixel = 16w + m
#pragma unroll
  for (int nt = 0; nt < 2; ++nt) {
    int oc = oh * 32 + nt * 16 + lm;
    float bias = bcomb[oc];
#pragma unroll
    for (int r = 0; r < 4; ++r) {
      int pd = 16 * w + 4 * lg + r;
      int gy = ty0 + (pd >> 3), gx = tx0 + (pd & 7);
      float v = (nt == 0 ? acc0[r] : acc1[r]) + bias;
      wfeat[(size_t)((b << 12) + gy * 64 + gx) * 64 + oc] = v;
    }
  }
}

// ---------------------------------------------------------------------------
// mean: per-(b,oc) mean of Wfeat via 16 pixel-segments, atomicAdd partials.
// ---------------------------------------------------------------------------
__global__ __launch_bounds__(256) void mean_kernel(const float* __restrict__ wfeat,
                                                   float* __restrict__ avg) {
  int bi = blockIdx.x;
  int b = bi >> 4, seg = bi & 15;
  int t = threadIdx.x;
  int oc = t & 63, sub = t >> 6;
  float s = 0.f;
  const float* p = wfeat + (size_t)((b << 12) + seg * 256 + sub * 64) * 64 + oc;
  for (int q = 0; q < 64; ++q) s += p[q * 64];
  __shared__ float red[256];
  red[t] = s;
  __syncthreads();
  if (t < 64) {
    float tot = red[t] + red[64 + t] + red[128 + t] + red[192 + t];
    atomicAdd(&avg[b * 64 + t], tot * (1.f / 4096.f));
  }
}

// ---------------------------------------------------------------------------
// gate: sigmoid(wa2 @ (wa1 @ avg + ba1) + ba2)
// ---------------------------------------------------------------------------
__global__ __launch_bounds__(64) void gate_kernel(
    const float* __restrict__ wa1, const float* __restrict__ ba1,
    const float* __restrict__ wa2, const float* __restrict__ ba2,
    const float* __restrict__ avg, float* __restrict__ gate) {
  int b = blockIdx.x;
  int t = threadIdx.x;
  __shared__ float av[64];
  __shared__ float tl[8];
  av[t] = avg[b * 64 + t];
  __syncthreads();
  if (t < 8) {
    float s = ba1[t];
    for (int i = 0; i < 64; ++i) s += wa1[t * 64 + i] * av[i];
    tl[t] = s;
  }
  __syncthreads();
  float s = ba2[t];
#pragma unroll
  for (int j = 0; j < 8; ++j) s += wa2[t * 8 + j] * tl[j];
  gate[b * 64 + t] = 1.f / (1.f + expf(-s));
}

// ---------------------------------------------------------------------------
// edge: depthwise 3x3 + gate on Wfeat (fp32, [pix][64]) -> Wpad4 (f16).
// Grid 64: bi = b*32 + g*2 + half (32-row halves). LDS [34][66] float4.
// ---------------------------------------------------------------------------
__global__ __launch_bounds__(256) void edge_kernel(
    const float* __restrict__ wedge, const float* __restrict__ wfeat,
    const float* __restrict__ gate, _Float16* __restrict__ wpad4) {
  __shared__ float4 tl[34 * 66];
  int bi = blockIdx.x;
  int b = bi >> 5;
  int r2 = bi & 31;
  int g = r2 >> 1, half = r2 & 1;
  int y0 = half * 32;
  for (int u = threadIdx.x; u < 2244; u += 256) {
    int r = u / 66, c = u % 66;
    int y = y0 + r - 1, x = c - 1;
    float4 v = {0.f, 0.f, 0.f, 0.f};
    if (y >= 0 && y < 64 && x >= 0 && x < 64)
      v = *(const float4*)&wfeat[(size_t)((b << 12) + y * 64 + x) * 64 + g * 4];
    tl[u] = v;
  }
  __syncthreads();
  float wk[9][4];
#pragma unroll
  for (int j = 0; j < 4; ++j)
#pragma unroll
    for (int k = 0; k < 9; ++k) wk[k][j] = wedge[(g * 4 + j) * 9 + k];
  float g4[4];
#pragma unroll
  for (int j = 0; j < 4; ++j) g4[j] = gate[b * 64 + g * 4 + j];

  for (int p = threadIdx.x; p < 2048; p += 256) {
    int r = p >> 6, x = p & 63;
    float e[4] = {0.f, 0.f, 0.f, 0.f};
#pragma unroll
    for (int ky = 0; ky < 3; ++ky) {
#pragma unroll
      for (int kx = 0; kx < 3; ++kx) {
        float4 v = tl[(r + ky) * 66 + x + kx];
        int k = ky * 3 + kx;
        e[0] = fmaf(wk[k][0], v.x, e[0]);
        e[1] = fmaf(wk[k][1], v.y, e[1]);
        e[2] = fmaf(wk[k][2], v.z, e[2]);
        e[3] = fmaf(wk[k][3], v.w, e[3]);
      }
    }
    float4 c = tl[(r + 1) * 66 + x + 1];
    f16x4 h;
    h[0] = (_Float16)(c.x * g4[0] + e[0]);
    h[1] = (_Float16)(c.y * g4[1] + e[1]);
    h[2] = (_Float16)(c.z * g4[2] + e[2]);
    h[3] = (_Float16)(c.w * g4[3] + e[3]);
    *(f16x4*)&wpad4[(((b * 16 + g) * 66 + y0 + r + 1) * 68 + x + 1) * 4] = h;
  }
}

// ---------------------------------------------------------------------------
// enc MFMA: 3x3 conv Wpad4 -> ENC[b][pix][112]. Grid (8,16,2), 128 thr =
// 2 waves; tile 8x4 pixels; 7 oc-tiles. LDS [16 g][6 r][10 c][4], g-str 272.
// ---------------------------------------------------------------------------
__global__ __launch_bounds__(128) void enc_kernel(
    const _Float16* __restrict__ wpad4, const f16x4* __restrict__ wfe,
    float* __restrict__ enc) {
  __shared__ _Float16 xs[16 * 272];
  const int tid = threadIdx.x;
  const int b = blockIdx.z;
  const int tx0 = blockIdx.x * 8, ty0 = blockIdx.y * 4;

  for (int u = tid; u < 960; u += 128) {
    int g = u / 60;
    int rem = u - g * 60;
    int r = rem / 10, c = rem - r * 10;
    f16x4 v = *(const f16x4*)&wpad4[(((b * 16 + g) * 66 + ty0 + r) * 68 + tx0 + c) * 4];
    *(f16x4*)&xs[g * 272 + r * 40 + c * 4] = v;
  }
  __syncthreads();

  const int w = tid >> 6, l = tid & 63;
  const int lm = l & 15, lg = l >> 4;
  const int p = 16 * w + lm;
  const int abase = (p >> 3) * 40 + (p & 7) * 4;
  const int lgoff = lg * 272;

  f32x4 acc[7];
#pragma unroll
  for (int nt = 0; nt < 7; ++nt) acc[nt] = (f32x4){0.f, 0.f, 0.f, 0.f};

  for (int dy = 0; dy < 3; ++dy) {
    for (int dx = 0; dx < 3; ++dx) {
      const int t = dy * 3 + dx;
      const int toff = abase + dy * 40 + dx * 4;
      const f16x4* wt = wfe + (t * 4) * 7 * 64 + l;
#pragma unroll
      for (int cc = 0; cc < 4; ++cc) {
        f16x4 a = *(const f16x4*)&xs[cc * 1088 + lgoff + toff];
#pragma unroll
        for (int nt = 0; nt < 7; ++nt) {
          f16x4 bb = wt[(cc * 7 + nt) * 64];
          acc[nt] = __builtin_amdgcn_mfma_f32_16x16x16f16(a, bb, acc[nt], 0, 0, 0);
        }
      }
    }
  }
#pragma unroll
  for (int nt = 0; nt < 7; ++nt) {
#pragma unroll
    for (int r = 0; r < 4; ++r) {
      int oc = nt * 16 + lm;
      if (oc < 100) {
        int pd = 16 * w + 4 * lg + r;
        int gy = ty0 + (pd >> 3), gx = tx0 + (pd & 7);
        enc[(size_t)((b << 12) + gy * 64 + gx) * 112 + oc] = acc[nt][r];
      }
    }
  }
}

// ---------------------------------------------------------------------------
// carafe: 4 softmaxes over 25 ENC logits per lo-res pixel, weighted gather
// of fp16 X. Grid (16,8,8): z = b*4 + cq (32-ch quarter). 256 thr =
// 32 pix x 8 slots (4 ch each).
// ---------------------------------------------------------------------------
__global__ __launch_bounds__(256) void carafe_kernel(
    const _Float16* __restrict__ xpad4, const float* __restrict__ enc,
    float* __restrict__ out) {
  const int tid = threadIdx.x;
  const int z = blockIdx.z;
  const int b = z >> 2, cq = z & 3;
  const int h0 = blockIdx.y * 8, w0 = blockIdx.x * 4;
  __shared__ __attribute__((aligned(16))) float smw[32 * 104];  // [pix][tap*4+sub]
  __shared__ _Float16 xt[8 * 432];  // [gg][12 r][8 c][4], row-str 36

  if (tid < 128) {
    int pix = tid & 31, sub = tid >> 5;
    int h = h0 + (pix >> 2), wv = w0 + (pix & 3);
    const float* encp = enc + (size_t)((b << 12) + h * 64 + wv) * 112 + sub;
    float lv[25];
    float m = -1e30f;
#pragma unroll
    for (int k = 0; k < 25; ++k) {
      lv[k] = encp[k * 4];
      m = fmaxf(m, lv[k]);
    }
    float s = 0.f;
#pragma unroll
    for (int k = 0; k < 25; ++k) {
      lv[k] = __expf(lv[k] - m);
      s += lv[k];
    }
    float inv = 1.f / s;
#pragma unroll
    for (int k = 0; k < 25; ++k) smw[pix * 104 + k * 4 + sub] = lv[k] * inv;
  }
  for (int u = tid; u < 768; u += 256) {
    int gg = u / 96;
    int rem = u - gg * 96;
    int r = rem >> 3, c = rem & 7;
    f16x4 v = *(const f16x4*)&xpad4[(((b * 32 + cq * 8 + gg) * 68 + h0 + r) * 72 + w0 + c) * 4];
    *(f16x4*)&xt[gg * 432 + r * 36 + c * 4] = v;
  }
  __syncthreads();

  const int slot = tid >> 5, pix = tid & 31;
  const int ph = pix >> 2, pw = pix & 3;
  const float* wbase = &smw[pix * 104];
  const _Float16* xbase = &xt[slot * 432];

  float acc[4][4];
#pragma unroll
  for (int s = 0; s < 4; ++s)
#pragma unroll
    for (int j = 0; j < 4; ++j) acc[s][j] = 0.f;

#pragma unroll
  for (int ki = 0; ki < 5; ++ki) {
#pragma unroll
    for (int kj = 0; kj < 5; ++kj) {
      int tap = ki * 5 + kj;
      float4 wv = *(const float4*)(wbase + tap * 4);
      f16x4 xh = *(const f16x4*)&xbase[(ph + ki) * 36 + (pw + kj) * 4];
#pragma unroll
      for (int j = 0; j < 4; ++j) {
        float xv = (float)xh[j];
        acc[0][j] = fmaf(wv.x, xv, acc[0][j]);
        acc[1][j] = fmaf(wv.y, xv, acc[1][j]);
        acc[2][j] = fmaf(wv.z, xv, acc[2][j]);
        acc[3][j] = fmaf(wv.w, xv, acc[3][j]);
      }
    }
  }
  int y0 = 2 * (h0 + ph), x0 = 2 * (w0 + pw);
#pragma unroll
  for (int j = 0; j < 4; ++j) {
    int c = cq * 32 + slot * 4 + j;
    float* op = out + ((size_t)(b * 128 + c) * 128 + y0) * 128 + x0;
    float2 v0 = {acc[0][j], acc[1][j]};
    float2 v1 = {acc[2][j], acc[3][j]};
    *(float2*)op = v0;
    *(float2*)(op + 128) = v1;
  }
}

// ---------------------------------------------------------------------------
extern "C" void kernel_launch(void* const* d_in, const int* in_sizes, int n_in,
                              void* d_out, int out_size, void* d_ws, size_t ws_size,
                              hipStream_t stream) {
  const float* X     = (const float*)d_in[0];
  const float* w3    = (const float*)d_in[1];
  const float* b3    = (const float*)d_in[2];
  const float* w5    = (const float*)d_in[3];
  const float* b5    = (const float*)d_in[4];
  const float* wa1   = (const float*)d_in[5];
  const float* ba1   = (const float*)d_in[6];
  const float* wa2   = (const float*)d_in[7];
  const float* ba2   = (const float*)d_in[8];
  const float* wedge = (const float*)d_in[9];
  const float* wenc  = (const float*)d_in[10];
  char* wsb = (char*)d_ws;  // ~9.96 MB
  float* out = (float*)d_out;

  _Float16* xpad4 = (_Float16*)(wsb + XPAD4_B);
  f16x4*    wfc   = (f16x4*)(wsb + WFC_B);
  f16x4*    wfe   = (f16x4*)(wsb + WFE_B);
  _Float16* wpad4 = (_Float16*)(wsb + WPAD4_B);
  float*    wfeat = (float*)(wsb + WFEAT_B);
  float*    enc   = (float*)(wsb + ENC_B);
  float*    bcomb = (float*)(wsb + BCOMB_B);
  float*    avg   = (float*)(wsb + AVG_B);
  float*    gate  = (float*)(wsb + GATE_B);

  prep_kernel<<<1224, 256, 0, stream>>>(X, w3, b3, w5, b5, wenc, wsb);
  convw_kernel<<<dim3(8, 8, 4), 256, 0, stream>>>(xpad4, wfc, bcomb, wfeat);
  mean_kernel<<<32, 256, 0, stream>>>(wfeat, avg);
  gate_kernel<<<2, 64, 0, stream>>>(wa1, ba1, wa2, ba2, avg, gate);
  edge_kernel<<<64, 256, 0, stream>>>(wedge, wfeat, gate, wpad4);
  enc_kernel<<<dim3(8, 16, 2), 128, 0, stream>>>(wpad4, wfe, enc);
  carafe_kernel<<<dim3(16, 8, 8), 256, 0, stream>>>(xpad4, enc, out);
}

// Round 5
// 72.318 us; speedup vs baseline: 3.5985x; 1.2137x over previous
//
#include <hip/hip_runtime.h>
#include <math.h>

typedef __attribute__((ext_vector_type(4))) _Float16 f16x4;
typedef __attribute__((ext_vector_type(8))) _Float16 f16x8;
typedef __attribute__((ext_vector_type(4))) float f32x4;

// Workspace byte offsets
#define XPAD4_B 0            // [2][32 g][68 y][72 x][4 ci] f16 (data at y+2,x+2)
#define WFC_B   2506752      // convw B-frags [25 t][8 cc][4 ntg][64 l][4] f16
#define WFE_B   2916352      // enc  B-frags [9 t][4 cc][7 nt][64 l][4] f16
#define WPAD4_B 3045376      // [2][16 g][66 y][68 x][4] f16 (data at y+1,x+1)
#define WFEAT_B 4194304      // [2][4096 pix][64 oc] f32
#define WSM_B   6291456      // [2][128 tile][25 tap][32 pix][4 sub] f16 softmax wts
#define BCOMB_B 7929856      // [64] f32
#define AVG_B   7930112      // [128] f32 (pre-seeded with bias; mean accumulated)
// total ~7.93 MB

// ---------------------------------------------------------------------------
// prep: Xpad4 (f16 channel-last-4), MFMA B-fragment packs, bias, avg seed.
// ---------------------------------------------------------------------------
__global__ __launch_bounds__(256) void prep_kernel(
    const float* __restrict__ X,
    const float* __restrict__ w3, const float* __restrict__ b3,
    const float* __restrict__ w5, const float* __restrict__ b5,
    const float* __restrict__ wenc, char* __restrict__ wsb) {
  int idx = blockIdx.x * 256 + threadIdx.x;
  // Xpad4: 2*32*68*72 = 313344 units of 4 f16
  if (idx < 313344) {
    int x = idx % 72;
    int t = idx / 72;
    int y = t % 68;
    int t2 = t / 68;
    int g = t2 & 31, b = t2 >> 5;
    int yy = y - 2, xx = x - 2;
    bool ok = (yy >= 0 && yy < 64 && xx >= 0 && xx < 64);
    f16x4 h;
#pragma unroll
    for (int j = 0; j < 4; ++j) {
      float v = ok ? X[((b * 128 + g * 4 + j) << 12) + yy * 64 + xx] : 0.f;
      h[j] = (_Float16)v;
    }
    *((f16x4*)(wsb + XPAD4_B) + idx) = h;
  }
  // convw frags: 25*8*4*64 = 51200 units
  if (idx < 51200) {
    int l = idx & 63;
    int t2 = idx >> 6;
    int ntg = t2 & 3;
    int t3 = t2 >> 2;
    int cc = t3 & 7;
    int t = t3 >> 3;  // tap 0..24
    int ky = t / 5, kx = t % 5;
    int oc = ntg * 16 + (l & 15);
    int ci0 = cc * 16 + (l >> 4) * 4;
    f16x4 h;
#pragma unroll
    for (int i = 0; i < 4; ++i) {
      int ci = ci0 + i;
      float v = w5[(oc * 128 + ci) * 25 + t];
      if (ky >= 1 && ky <= 3 && kx >= 1 && kx <= 3)
        v += w3[(oc * 128 + ci) * 9 + (ky - 1) * 3 + (kx - 1)];
      h[i] = (_Float16)v;
    }
    *((f16x4*)(wsb + WFC_B) + idx) = h;
  }
  // enc frags: 9*4*7*64 = 16128 units
  if (idx < 16128) {
    int l = idx & 63;
    int t2 = idx >> 6;
    int nt = t2 % 7;
    int t3 = t2 / 7;
    int cc = t3 & 3;
    int t = t3 >> 2;  // tap 0..8
    int oc = nt * 16 + (l & 15);
    int ci0 = cc * 16 + (l >> 4) * 4;
    f16x4 h;
#pragma unroll
    for (int i = 0; i < 4; ++i) {
      float v = (oc < 100) ? wenc[(oc * 64 + ci0 + i) * 9 + t] : 0.f;
      h[i] = (_Float16)v;
    }
    *((f16x4*)(wsb + WFE_B) + idx) = h;
  }
  if (idx < 64) ((float*)(wsb + BCOMB_B))[idx] = b3[idx] + b5[idx];
  if (idx < 128) ((float*)(wsb + AVG_B))[idx] = b3[idx & 63] + b5[idx & 63];
}

// ---------------------------------------------------------------------------
// convw MFMA + fused mean. Grid (8,16,4): z = b*2 + oh. 256 thr = 4 waves:
// wave (pg = w&1 pixel half, og = w>>1 oc 16-group). Tile 8x4 px, 32 oc.
// LDS: [32 g][8 r][12 c][4] f16, g-stride 392.
// ---------------------------------------------------------------------------
__global__ __launch_bounds__(256) void convw_kernel(
    const _Float16* __restrict__ xpad4, const f16x4* __restrict__ wfc,
    const float* __restrict__ bcomb, float* __restrict__ wfeat,
    float* __restrict__ avg) {
  __shared__ _Float16 xs[32 * 392];
  __shared__ float red[64];
  const int tid = threadIdx.x;
  const int z = blockIdx.z;
  const int b = z >> 1, oh = z & 1;
  const int tx0 = blockIdx.x * 8, ty0 = blockIdx.y * 4;

  for (int u = tid; u < 3072; u += 256) {
    int g = u / 96;
    int rem = u - g * 96;
    int r = rem / 12, c = rem - r * 12;
    f16x4 v = *(const f16x4*)&xpad4[(((b * 32 + g) * 68 + ty0 + r) * 72 + tx0 + c) * 4];
    *(f16x4*)&xs[g * 392 + r * 48 + c * 4] = v;
  }
  __syncthreads();

  const int w = __builtin_amdgcn_readfirstlane(tid >> 6);
  const int l = tid & 63;
  const int pg = w & 1, og = w >> 1;
  const int lm = l & 15, lg = l >> 4;
  const int p = pg * 16 + lm;
  const int abase = (p >> 3) * 48 + (p & 7) * 4;

  f32x4 acc = {0.f, 0.f, 0.f, 0.f};
  for (int dy = 0; dy < 5; ++dy) {
    for (int dx = 0; dx < 5; ++dx) {
      const int t = dy * 5 + dx;
      const int toff = abase + dy * 48 + dx * 4;
      const f16x4* wt = wfc + (t * 32 + oh * 2 + og) * 64 + l;
#pragma unroll
      for (int cc = 0; cc < 8; ++cc) {
        f16x4 a = *(const f16x4*)&xs[(cc * 4 + lg) * 392 + toff];
        f16x4 bb = wt[cc * 256];
        acc = __builtin_amdgcn_mfma_f32_16x16x16f16(a, bb, acc, 0, 0, 0);
      }
    }
  }
  const int oc = oh * 32 + og * 16 + lm;
  const float bias = bcomb[oc];
#pragma unroll
  for (int r = 0; r < 4; ++r) {
    int pd = pg * 16 + 4 * lg + r;
    int gy = ty0 + (pd >> 3), gx = tx0 + (pd & 7);
    wfeat[(size_t)((b << 12) + gy * 64 + gx) * 64 + oc] = acc[r] + bias;
  }
  // fused mean partial (bias excluded; avg pre-seeded with bias)
  float s = acc[0] + acc[1] + acc[2] + acc[3];
  s += __shfl_xor(s, 16);
  s += __shfl_xor(s, 32);
  if (lg == 0) red[(og * 16 + lm) * 2 + pg] = s;
  __syncthreads();
  if (tid < 32) {
    float tot = red[tid * 2] + red[tid * 2 + 1];
    atomicAdd(&avg[b * 64 + oh * 32 + tid], tot * (1.f / 4096.f));
  }
}

// ---------------------------------------------------------------------------
// edge: gate recompute + depthwise 3x3 + gate apply -> Wpad4 f16 (+borders).
// Grid 64: bi = b*32 + g*2 + half.
// ---------------------------------------------------------------------------
__global__ __launch_bounds__(256) void edge_kernel(
    const float* __restrict__ wedge,
    const float* __restrict__ wa1, const float* __restrict__ ba1,
    const float* __restrict__ wa2, const float* __restrict__ ba2,
    const float* __restrict__ avg, const float* __restrict__ wfeat,
    _Float16* __restrict__ wpad4) {
  __shared__ float4 tl[34 * 66];
  __shared__ float av[64], tlat[8], gsh[4];
  const int tid = threadIdx.x;
  const int bi = blockIdx.x;
  const int b = bi >> 5;
  const int r2 = bi & 31;
  const int g = r2 >> 1, half = r2 & 1;
  const int y0 = half * 32;

  if (tid < 64) av[tid] = avg[b * 64 + tid];
  for (int u = tid; u < 2244; u += 256) {
    int r = u / 66, c = u % 66;
    int y = y0 + r - 1, x = c - 1;
    float4 v = {0.f, 0.f, 0.f, 0.f};
    if (y >= 0 && y < 64 && x >= 0 && x < 64)
      v = *(const float4*)&wfeat[(size_t)((b << 12) + y * 64 + x) * 64 + g * 4];
    tl[u] = v;
  }
  __syncthreads();
  if (tid < 8) {
    float s = ba1[tid];
    for (int i = 0; i < 64; ++i) s += wa1[tid * 64 + i] * av[i];
    tlat[tid] = s;
  }
  __syncthreads();
  if (tid < 4) {
    int c = g * 4 + tid;
    float s = ba2[c];
#pragma unroll
    for (int j = 0; j < 8; ++j) s += wa2[c * 8 + j] * tlat[j];
    gsh[tid] = 1.f / (1.f + expf(-s));
  }
  __syncthreads();

  float wk[9][4];
#pragma unroll
  for (int j = 0; j < 4; ++j)
#pragma unroll
    for (int k = 0; k < 9; ++k) wk[k][j] = wedge[(g * 4 + j) * 9 + k];
  float g4[4];
#pragma unroll
  for (int j = 0; j < 4; ++j) g4[j] = gsh[j];

  _Float16* plane = wpad4 + (size_t)(b * 16 + g) * 66 * 68 * 4;
  for (int pp = tid; pp < 2048; pp += 256) {
    int r = pp >> 6, x = pp & 63;
    float e[4] = {0.f, 0.f, 0.f, 0.f};
#pragma unroll
    for (int ky = 0; ky < 3; ++ky) {
#pragma unroll
      for (int kx = 0; kx < 3; ++kx) {
        float4 v = tl[(r + ky) * 66 + x + kx];
        int k = ky * 3 + kx;
        e[0] = fmaf(wk[k][0], v.x, e[0]);
        e[1] = fmaf(wk[k][1], v.y, e[1]);
        e[2] = fmaf(wk[k][2], v.z, e[2]);
        e[3] = fmaf(wk[k][3], v.w, e[3]);
      }
    }
    float4 c = tl[(r + 1) * 66 + x + 1];
    f16x4 h;
    h[0] = (_Float16)(c.x * g4[0] + e[0]);
    h[1] = (_Float16)(c.y * g4[1] + e[1]);
    h[2] = (_Float16)(c.z * g4[2] + e[2]);
    h[3] = (_Float16)(c.w * g4[3] + e[3]);
    *(f16x4*)&plane[((y0 + r + 1) * 68 + x + 1) * 4] = h;
  }
  // border zeros: full row (0 or 65) + cols {0,65,66,67} of this half's rows
  f16x4 zz = {(_Float16)0.f, (_Float16)0.f, (_Float16)0.f, (_Float16)0.f};
  for (int u = tid; u < 196; u += 256) {
    int r, c;
    if (u < 68) {
      r = half ? 65 : 0;
      c = u;
    } else {
      int v = u - 68;
      r = y0 + 1 + (v >> 2);
      int cm = v & 3;
      c = (cm == 0) ? 0 : (64 + cm);
    }
    *(f16x4*)&plane[(r * 68 + c) * 4] = zz;
  }
}

// ---------------------------------------------------------------------------
// enc MFMA + fused softmax -> WSM f16 [b][tile][25][32][4].
// Grid (8,16,2). 256 thr = 4 waves: (pg = w&1, hs = w>>1 nt-half).
// Tile 8x4 px. LDS xs [16 g][6 r][10 c][4] g-str 272; sml [32][116] f32.
// ---------------------------------------------------------------------------
__global__ __launch_bounds__(256) void enc_kernel(
    const _Float16* __restrict__ wpad4, const f16x4* __restrict__ wfe,
    _Float16* __restrict__ wsm) {
  __shared__ _Float16 xs[16 * 272];
  __shared__ float sml[32 * 116];
  const int tid = threadIdx.x;
  const int b = blockIdx.z;
  const int tx0 = blockIdx.x * 8, ty0 = blockIdx.y * 4;

  for (int u = tid; u < 960; u += 256) {
    int g = u / 60;
    int rem = u - g * 60;
    int r = rem / 10, c = rem - r * 10;
    f16x4 v = *(const f16x4*)&wpad4[(((b * 16 + g) * 66 + ty0 + r) * 68 + tx0 + c) * 4];
    *(f16x4*)&xs[g * 272 + r * 40 + c * 4] = v;
  }
  __syncthreads();

  const int w = __builtin_amdgcn_readfirstlane(tid >> 6);
  const int l = tid & 63;
  const int pg = w & 1, hs = w >> 1;
  const int lm = l & 15, lg = l >> 4;
  const int p = pg * 16 + lm;
  const int abase = (p >> 3) * 40 + (p & 7) * 4;
  const int n0 = hs * 4, nn = hs ? 3 : 4;

  f32x4 acc[4];
#pragma unroll
  for (int i = 0; i < 4; ++i) acc[i] = (f32x4){0.f, 0.f, 0.f, 0.f};

  for (int dy = 0; dy < 3; ++dy) {
    for (int dx = 0; dx < 3; ++dx) {
      const int t = dy * 3 + dx;
      const int toff = abase + dy * 40 + dx * 4;
#pragma unroll
      for (int cc = 0; cc < 4; ++cc) {
        f16x4 a = *(const f16x4*)&xs[(cc * 4 + lg) * 272 + toff];
#pragma unroll
        for (int ntl = 0; ntl < 4; ++ntl) {
          if (ntl < nn) {
            f16x4 bb = wfe[((t * 4 + cc) * 7 + n0 + ntl) * 64 + l];
            acc[ntl] = __builtin_amdgcn_mfma_f32_16x16x16f16(a, bb, acc[ntl], 0, 0, 0);
          }
        }
      }
    }
  }
#pragma unroll
  for (int ntl = 0; ntl < 4; ++ntl) {
    if (ntl < nn) {
#pragma unroll
      for (int r = 0; r < 4; ++r)
        sml[(pg * 16 + 4 * lg + r) * 116 + (n0 + ntl) * 16 + lm] = acc[ntl][r];
    }
  }
  __syncthreads();
  if (tid < 128) {
    int pix = tid >> 2, sub = tid & 3;
    float lv[25];
    float m = -1e30f;
#pragma unroll
    for (int k = 0; k < 25; ++k) {
      lv[k] = sml[pix * 116 + k * 4 + sub];
      m = fmaxf(m, lv[k]);
    }
    float s = 0.f;
#pragma unroll
    for (int k = 0; k < 25; ++k) {
      lv[k] = __expf(lv[k] - m);
      s += lv[k];
    }
    float inv = 1.f / s;
    int tile = blockIdx.y * 8 + blockIdx.x;
    _Float16* dst = wsm + (size_t)((b * 128 + tile) * 25) * 128 + pix * 4 + sub;
#pragma unroll
    for (int k = 0; k < 25; ++k) dst[k * 128] = (_Float16)(lv[k] * inv);
  }
}

// ---------------------------------------------------------------------------
// carafe: read WSM weights (tile-matched), gather f16 X, write out.
// Grid (8,16,8): z = b*4 + cq. 256 thr = 32 pix (8x4 tile) x 8 slots (4 ch).
// ---------------------------------------------------------------------------
__global__ __launch_bounds__(256) void carafe_kernel(
    const _Float16* __restrict__ xpad4, const _Float16* __restrict__ wsm,
    float* __restrict__ out) {
  const int tid = threadIdx.x;
  const int z = blockIdx.z;
  const int b = z >> 2, cq = z & 3;
  const int h0 = blockIdx.y * 4, w0 = blockIdx.x * 8;
  const int tile = blockIdx.y * 8 + blockIdx.x;
  __shared__ _Float16 wsl[3200];      // [25 tap][32 pix][4 sub]
  __shared__ _Float16 xt[8 * 392];    // [8 g][8 r][12 c][4], g-str 392

  for (int u = tid; u < 400; u += 256)
    ((f16x8*)wsl)[u] = ((const f16x8*)(wsm + (size_t)((b * 128 + tile) * 25) * 128))[u];
  for (int u = tid; u < 768; u += 256) {
    int gg = u / 96;
    int rem = u - gg * 96;
    int r = rem / 12, c = rem - r * 12;
    f16x4 v = *(const f16x4*)&xpad4[(((b * 32 + cq * 8 + gg) * 68 + h0 + r) * 72 + w0 + c) * 4];
    *(f16x4*)&xt[gg * 392 + r * 48 + c * 4] = v;
  }
  __syncthreads();

  const int slot = tid >> 5, pix = tid & 31;
  const int py = pix >> 3, px = pix & 7;
  const _Float16* xbase = &xt[slot * 392];

  float acc[4][4];
#pragma unroll
  for (int s = 0; s < 4; ++s)
#pragma unroll
    for (int j = 0; j < 4; ++j) acc[s][j] = 0.f;

#pragma unroll
  for (int ki = 0; ki < 5; ++ki) {
#pragma unroll
    for (int kj = 0; kj < 5; ++kj) {
      int tap = ki * 5 + kj;
      f16x4 wh = *(const f16x4*)&wsl[tap * 128 + pix * 4];
      f16x4 xh = *(const f16x4*)&xbase[(py + ki) * 48 + (px + kj) * 4];
      float w0f = (float)wh[0], w1f = (float)wh[1], w2f = (float)wh[2], w3f = (float)wh[3];
#pragma unroll
      for (int j = 0; j < 4; ++j) {
        float xv = (float)xh[j];
        acc[0][j] = fmaf(w0f, xv, acc[0][j]);
        acc[1][j] = fmaf(w1f, xv, acc[1][j]);
        acc[2][j] = fmaf(w2f, xv, acc[2][j]);
        acc[3][j] = fmaf(w3f, xv, acc[3][j]);
      }
    }
  }
  int y0 = 2 * (h0 + py), x0 = 2 * (w0 + px);
#pragma unroll
  for (int j = 0; j < 4; ++j) {
    int c = cq * 32 + slot * 4 + j;
    float* op = out + ((size_t)(b * 128 + c) * 128 + y0) * 128 + x0;
    float2 v0 = {acc[0][j], acc[1][j]};
    float2 v1 = {acc[2][j], acc[3][j]};
    *(float2*)op = v0;
    *(float2*)(op + 128) = v1;
  }
}

// ---------------------------------------------------------------------------
extern "C" void kernel_launch(void* const* d_in, const int* in_sizes, int n_in,
                              void* d_out, int out_size, void* d_ws, size_t ws_size,
                              hipStream_t stream) {
  const float* X     = (const float*)d_in[0];
  const float* w3    = (const float*)d_in[1];
  const float* b3    = (const float*)d_in[2];
  const float* w5    = (const float*)d_in[3];
  const float* b5    = (const float*)d_in[4];
  const float* wa1   = (const float*)d_in[5];
  const float* ba1   = (const float*)d_in[6];
  const float* wa2   = (const float*)d_in[7];
  const float* ba2   = (const float*)d_in[8];
  const float* wedge = (const float*)d_in[9];
  const float* wenc  = (const float*)d_in[10];
  char* wsb = (char*)d_ws;  // ~7.93 MB
  float* out = (float*)d_out;

  _Float16* xpad4 = (_Float16*)(wsb + XPAD4_B);
  f16x4*    wfc   = (f16x4*)(wsb + WFC_B);
  f16x4*    wfe   = (f16x4*)(wsb + WFE_B);
  _Float16* wpad4 = (_Float16*)(wsb + WPAD4_B);
  float*    wfeat = (float*)(wsb + WFEAT_B);
  _Float16* wsm   = (_Float16*)(wsb + WSM_B);
  float*    bcomb = (float*)(wsb + BCOMB_B);
  float*    avg   = (float*)(wsb + AVG_B);

  prep_kernel<<<1224, 256, 0, stream>>>(X, w3, b3, w5, b5, wenc, wsb);
  convw_kernel<<<dim3(8, 16, 4), 256, 0, stream>>>(xpad4, wfc, bcomb, wfeat, avg);
  edge_kernel<<<64, 256, 0, stream>>>(wedge, wa1, ba1, wa2, ba2, avg, wfeat, wpad4);
  enc_kernel<<<dim3(8, 16, 2), 256, 0, stream>>>(wpad4, wfe, wsm);
  carafe_kernel<<<dim3(8, 16, 8), 256, 0, stream>>>(xpad4, wsm, out);
}

// Round 6
// 51.614 us; speedup vs baseline: 5.0420x; 1.4011x over previous
//
#include <hip/hip_runtime.h>
#include <math.h>

typedef __attribute__((ext_vector_type(4))) _Float16 f16x4;
typedef __attribute__((ext_vector_type(8))) _Float16 f16x8;
typedef __attribute__((ext_vector_type(4))) float f32x4;

// Workspace byte offsets
#define XPAD8_B  0           // [2][16 gg][68 y][72 x][8 ci] f16 (data at y+2,x+2)
#define WFC_B    2506752     // convw B-frags [25 t][4 cc][4 ntg][64 l] f16x8
#define WFE_B    2916352     // enc  B-frags [9 t][2 cc][7 nt][64 l] f16x8
#define WFEATP_B 3045376     // [2][8 gg][66][68][8] f16 pre-edge W (data at +1,+1)
#define WPADP_B  4194304     // [2][8 gg][66][68][8] f16 post-edge V
#define BCOMB_B  5343232     // [64] f32
#define AVG_B    5343488     // [128] f32 (seeded with bias)
// total ~5.34 MB

// ---------------------------------------------------------------------------
// prep: Xpad8, MFMA B-frag packs (K=32), border zeros, bias, avg seed.
// ---------------------------------------------------------------------------
__global__ __launch_bounds__(256) void prep_kernel(
    const float* __restrict__ X,
    const float* __restrict__ w3, const float* __restrict__ b3,
    const float* __restrict__ w5, const float* __restrict__ b5,
    const float* __restrict__ wenc, char* __restrict__ wsb) {
  int idx = blockIdx.x * 256 + threadIdx.x;
  // Xpad8: [2][16][68][72] units of 8 ch
  if (idx < 156672) {
    int x = idx % 72;
    int t = idx / 72;
    int y = t % 68;
    int t2 = t / 68;
    int gg = t2 & 15, b = t2 >> 4;
    int yy = y - 2, xx = x - 2;
    bool ok = (yy >= 0 && yy < 64 && xx >= 0 && xx < 64);
    f16x8 h;
#pragma unroll
    for (int j = 0; j < 8; ++j) {
      float v = ok ? X[((b * 128 + gg * 8 + j) << 12) + yy * 64 + xx] : 0.f;
      h[j] = (_Float16)v;
    }
    ((f16x8*)(wsb + XPAD8_B))[idx] = h;
  }
  // convw frags: idx = ((t*4+cc)*4+ntg)*64 + l, 25600 units
  if (idx < 25600) {
    int l = idx & 63;
    int q = idx >> 6;
    int ntg = q & 3;
    int q2 = q >> 2;
    int cc = q2 & 3;
    int t = q2 >> 2;
    int ky = t / 5, kx = t % 5;
    int oc = ntg * 16 + (l & 15);
    int ci0 = cc * 32 + (l >> 4) * 8;
    f16x8 h;
#pragma unroll
    for (int i = 0; i < 8; ++i) {
      int ci = ci0 + i;
      float v = w5[(oc * 128 + ci) * 25 + t];
      if (ky >= 1 && ky <= 3 && kx >= 1 && kx <= 3)
        v += w3[(oc * 128 + ci) * 9 + (ky - 1) * 3 + (kx - 1)];
      h[i] = (_Float16)v;
    }
    ((f16x8*)(wsb + WFC_B))[idx] = h;
  }
  // enc frags: idx = ((t*2+cc)*7+nt)*64 + l, 8064 units
  if (idx < 8064) {
    int l = idx & 63;
    int q = idx >> 6;
    int nt = q % 7;
    int q2 = q / 7;
    int cc = q2 & 1;
    int t = q2 >> 1;
    int oc = nt * 16 + (l & 15);
    int ci0 = cc * 32 + (l >> 4) * 8;
    f16x8 h;
#pragma unroll
    for (int i = 0; i < 8; ++i) {
      float v = (oc < 100) ? wenc[(oc * 64 + ci0 + i) * 9 + t] : 0.f;
      h[i] = (_Float16)v;
    }
    ((f16x8*)(wsb + WFE_B))[idx] = h;
  }
  // border zeros for wfeatP and wpadP: 2 bufs x 16 planes x 392 positions
  if (idx < 12544) {
    _Float16* base = (_Float16*)(wsb + ((idx < 6272) ? WFEATP_B : WPADP_B));
    int v = idx % 6272;
    int plane = v / 392, p = v % 392;
    int r, c;
    if (p < 136) {
      r = (p >= 68) ? 65 : 0;
      c = p % 68;
    } else {
      int q = p - 136;
      r = 1 + (q >> 2);
      int cm = q & 3;
      c = (cm == 0) ? 0 : (64 + cm);
    }
    f16x8 z = {(_Float16)0.f, (_Float16)0.f, (_Float16)0.f, (_Float16)0.f,
               (_Float16)0.f, (_Float16)0.f, (_Float16)0.f, (_Float16)0.f};
    *(f16x8*)&base[((size_t)(plane * 66 + r) * 68 + c) * 8] = z;
  }
  if (idx < 64) ((float*)(wsb + BCOMB_B))[idx] = b3[idx] + b5[idx];
  if (idx < 128) ((float*)(wsb + AVG_B))[idx] = b3[idx & 63] + b5[idx & 63];
}

// ---------------------------------------------------------------------------
// convw: 5x5 conv via mfma 16x16x32, 2 acc chains, fused mean, LDS repack
// to channel-last-8 padded output. Grid (8,16,4): z = b*2 + oh.
// Waves: (pg = w&1 pixel 16-group, og = w>>1 oc 16-group).
// ---------------------------------------------------------------------------
__global__ __launch_bounds__(256) void convw_kernel(
    const _Float16* __restrict__ xpad8, const f16x8* __restrict__ wfc,
    const float* __restrict__ bcomb, _Float16* __restrict__ wfeatp,
    float* __restrict__ avg) {
  __shared__ _Float16 xs[16 * 776];  // [gg][8r][12c][8], gg-stride 776
  __shared__ float red2[2][32];
  const int tid = threadIdx.x;
  const int z = blockIdx.z;
  const int b = z >> 1, oh = z & 1;
  const int tx0 = blockIdx.x * 8, ty0 = blockIdx.y * 4;

  // stage 16gg x 8r x 12c units of 8 f16
  for (int u = tid; u < 1536; u += 256) {
    int gg = u / 96;
    int rem = u - gg * 96;
    int r = rem / 12, c = rem - r * 12;
    f16x8 v = *(const f16x8*)&xpad8[((size_t)((b * 16 + gg) * 68 + ty0 + r) * 72 + tx0 + c) * 8];
    *(f16x8*)&xs[gg * 776 + r * 96 + c * 8] = v;
  }
  __syncthreads();

  const int w = __builtin_amdgcn_readfirstlane(tid >> 6);
  const int l = tid & 63;
  const int pg = w & 1, og = w >> 1;
  const int lm = l & 15, lg = l >> 4;
  const int p = pg * 16 + lm;
  const int abase = (p >> 3) * 96 + (p & 7) * 8;
  const int ntg = oh * 2 + og;

  f32x4 accA = {0.f, 0.f, 0.f, 0.f}, accB = {0.f, 0.f, 0.f, 0.f};
  for (int dy = 0; dy < 5; ++dy) {
    for (int dx = 0; dx < 5; ++dx) {
      const int t = dy * 5 + dx;
      const int toff = abase + dy * 96 + dx * 8;
      const f16x8* wt = wfc + (t * 16 + ntg) * 64 + l;  // + cc*4*64
#pragma unroll
      for (int cc = 0; cc < 4; ++cc) {
        f16x8 a = *(const f16x8*)&xs[(cc * 4 + lg) * 776 + toff];
        f16x8 bb = wt[cc * 256];
        if (cc & 1)
          accB = __builtin_amdgcn_mfma_f32_16x16x32_f16(a, bb, accB, 0, 0, 0);
        else
          accA = __builtin_amdgcn_mfma_f32_16x16x32_f16(a, bb, accA, 0, 0, 0);
      }
    }
  }
  f32x4 acc = accA + accB;

  // fused mean partial (pre-bias)
  float s = acc[0] + acc[1] + acc[2] + acc[3];
  s += __shfl_xor(s, 16);
  s += __shfl_xor(s, 32);

  const int oc = ntg * 16 + lm;
  const float bias = bcomb[oc];
  __syncthreads();  // xs free for repack
  // repack: rep[pd 32][oc 64] f16, stride 72 (alias xs)
#pragma unroll
  for (int r = 0; r < 4; ++r) {
    int pd = pg * 16 + 4 * lg + r;
    xs[pd * 72 + oc] = (_Float16)(acc[r] + bias);
  }
  if (lg == 0) red2[pg][og * 16 + lm] = s;
  __syncthreads();
  if (tid < 32) {
    float tot = red2[0][tid] + red2[1][tid];
    atomicAdd(&avg[b * 64 + oh * 32 + tid], tot * (1.f / 4096.f));
  }
  // store: 256 thr = 32 pd x 8 gg-halves -> but only this oh's 32 oc:
  // units: 32 pd x 4 gg (gg = oh*4 + g2)
  if (tid < 128) {
    int g2 = tid >> 5, pd = tid & 31;
    int gg = oh * 4 + g2;
    f16x8 v = *(const f16x8*)&xs[pd * 72 + oh * 32 + g2 * 8];
    int gy = ty0 + (pd >> 3), gx = tx0 + (pd & 7);
    *(f16x8*)&wfeatp[((size_t)((b * 8 + gg) * 66 + 1 + gy) * 68 + 1 + gx) * 8] = v;
  }
}

// ---------------------------------------------------------------------------
// edge: gate recompute + depthwise 3x3 + gate apply. wfeatP -> wpadP (f16x8).
// Grid 64: bi = b*32 + gg*4 + band (16-row bands). 256 thr.
// ---------------------------------------------------------------------------
__global__ __launch_bounds__(256) void edge_kernel(
    const float* __restrict__ wedge,
    const float* __restrict__ wa1, const float* __restrict__ ba1,
    const float* __restrict__ wa2, const float* __restrict__ ba2,
    const float* __restrict__ avg, const _Float16* __restrict__ wfeatp,
    _Float16* __restrict__ wpadp) {
  __shared__ _Float16 ts[18 * 68 * 8];
  __shared__ float av[64], tlat[8], gsh[8];
  const int tid = threadIdx.x;
  const int bi = blockIdx.x;
  const int b = bi >> 5;
  const int r2 = bi & 31;
  const int gg = r2 >> 2, band = r2 & 3;
  const int y0 = band * 16;

  if (tid < 64) av[tid] = avg[b * 64 + tid];
  for (int u = tid; u < 1224; u += 256) {
    int r = u / 68, c = u - (u / 68) * 68;
    f16x8 v = *(const f16x8*)&wfeatp[((size_t)((b * 8 + gg) * 66 + y0 + r) * 68 + c) * 8];
    *(f16x8*)&ts[(r * 68 + c) * 8] = v;
  }
  __syncthreads();
  if (tid < 8) {
    float s = ba1[tid];
    for (int i = 0; i < 64; ++i) s += wa1[tid * 64 + i] * av[i];
    tlat[tid] = s;
  }
  __syncthreads();
  if (tid < 8) {
    int c = gg * 8 + tid;
    float s = ba2[c];
#pragma unroll
    for (int j = 0; j < 8; ++j) s += wa2[c * 8 + j] * tlat[j];
    gsh[tid] = 1.f / (1.f + expf(-s));
  }
  __syncthreads();

  float wk[9][8];
#pragma unroll
  for (int j = 0; j < 8; ++j)
#pragma unroll
    for (int k = 0; k < 9; ++k) wk[k][j] = wedge[(gg * 8 + j) * 9 + k];
  float g8[8];
#pragma unroll
  for (int j = 0; j < 8; ++j) g8[j] = gsh[j];

  for (int u = tid; u < 1024; u += 256) {
    int r = u >> 6, x = u & 63;
    f16x8 ctr = *(const f16x8*)&ts[((r + 1) * 68 + x + 1) * 8];
    float vout[8];
#pragma unroll
    for (int j = 0; j < 8; ++j) vout[j] = (float)ctr[j] * g8[j];
#pragma unroll
    for (int ky = 0; ky < 3; ++ky) {
#pragma unroll
      for (int kx = 0; kx < 3; ++kx) {
        f16x8 tv = *(const f16x8*)&ts[((r + ky) * 68 + x + kx) * 8];
        int k = ky * 3 + kx;
#pragma unroll
        for (int j = 0; j < 8; ++j) vout[j] = fmaf(wk[k][j], (float)tv[j], vout[j]);
      }
    }
    f16x8 h;
#pragma unroll
    for (int j = 0; j < 8; ++j) h[j] = (_Float16)vout[j];
    *(f16x8*)&wpadp[((size_t)((b * 8 + gg) * 66 + 1 + y0 + r) * 68 + 1 + x) * 8] = h;
  }
}

// ---------------------------------------------------------------------------
// enccarafe: enc 3x3 MFMA (K=576) + softmax + carafe gather, fused.
// Grid (8,16,2): z = b. 512 thr = 8 waves.
// MFMA waves: (pg = w&1, hs = w>>1): hs<3 -> 2 nt, hs==3 -> 1 nt.
// Carafe: 512 thr = 32 pix x 16 slots (8 ch each).
// ---------------------------------------------------------------------------
__global__ __launch_bounds__(512) void enccarafe_kernel(
    const _Float16* __restrict__ wpadp, const f16x8* __restrict__ wfe,
    const _Float16* __restrict__ xpad8, float* __restrict__ out) {
  __shared__ _Float16 xsv[8 * 488];   // [gg][6r][10c][8], gg-stride 488
  __shared__ float sml[32 * 116];     // [pix][oc]
  __shared__ _Float16 smw[25 * 128];  // [tap][pix][4 sub]
  __shared__ _Float16 xt[16 * 776];   // [gg][8r][12c][8], gg-stride 776
  const int tid = threadIdx.x;
  const int b = blockIdx.z;
  const int tx0 = blockIdx.x * 8, ty0 = blockIdx.y * 4;

  // stage V tile (480 units) and X tile (1536 units)
  for (int u = tid; u < 480; u += 512) {
    int gg = u / 60;
    int rem = u - gg * 60;
    int r = rem / 10, c = rem - r * 10;
    f16x8 v = *(const f16x8*)&wpadp[((size_t)((b * 8 + gg) * 66 + ty0 + r) * 68 + tx0 + c) * 8];
    *(f16x8*)&xsv[gg * 488 + r * 80 + c * 8] = v;
  }
  for (int u = tid; u < 1536; u += 512) {
    int gg = u / 96;
    int rem = u - gg * 96;
    int r = rem / 12, c = rem - r * 12;
    f16x8 v = *(const f16x8*)&xpad8[((size_t)((b * 16 + gg) * 68 + ty0 + r) * 72 + tx0 + c) * 8];
    *(f16x8*)&xt[gg * 776 + r * 96 + c * 8] = v;
  }
  __syncthreads();

  // ---- enc MFMA ----
  {
    const int w = __builtin_amdgcn_readfirstlane(tid >> 6);
    const int l = tid & 63;
    const int pg = w & 1, hs = w >> 1;
    const int lm = l & 15, lg = l >> 4;
    const int p = pg * 16 + lm;
    const int abase = (p >> 3) * 80 + (p & 7) * 8;
    const int nt0 = hs * 2;
    const int ncnt = (hs == 3) ? 1 : 2;

    f32x4 a0 = {0.f, 0.f, 0.f, 0.f}, a1 = {0.f, 0.f, 0.f, 0.f};
    for (int dy = 0; dy < 3; ++dy) {
      for (int dx = 0; dx < 3; ++dx) {
        const int t = dy * 3 + dx;
        const int toff = abase + dy * 80 + dx * 8;
#pragma unroll
        for (int cc = 0; cc < 2; ++cc) {
          f16x8 a = *(const f16x8*)&xsv[(cc * 4 + lg) * 488 + toff];
          f16x8 b0 = wfe[((t * 2 + cc) * 7 + nt0) * 64 + l];
          a0 = __builtin_amdgcn_mfma_f32_16x16x32_f16(a, b0, a0, 0, 0, 0);
          if (ncnt == 2) {
            f16x8 b1 = wfe[((t * 2 + cc) * 7 + nt0 + 1) * 64 + l];
            a1 = __builtin_amdgcn_mfma_f32_16x16x32_f16(a, b1, a1, 0, 0, 0);
          }
        }
      }
    }
#pragma unroll
    for (int r = 0; r < 4; ++r) {
      int pd = pg * 16 + 4 * lg + r;
      sml[pd * 116 + nt0 * 16 + lm] = a0[r];
      if (ncnt == 2) sml[pd * 116 + (nt0 + 1) * 16 + lm] = a1[r];
    }
  }
  __syncthreads();

  // ---- softmax over 25 taps x 4 subpix ----
  if (tid < 128) {
    int pix = tid >> 2, sub = tid & 3;
    float lv[25];
    float m = -1e30f;
#pragma unroll
    for (int k = 0; k < 25; ++k) {
      lv[k] = sml[pix * 116 + k * 4 + sub];
      m = fmaxf(m, lv[k]);
    }
    float s = 0.f;
#pragma unroll
    for (int k = 0; k < 25; ++k) {
      lv[k] = __expf(lv[k] - m);
      s += lv[k];
    }
    float inv = 1.f / s;
#pragma unroll
    for (int k = 0; k < 25; ++k) smw[k * 128 + pix * 4 + sub] = (_Float16)(lv[k] * inv);
  }
  __syncthreads();

  // ---- carafe gather ----
  {
    const int slot = tid >> 5, pix = tid & 31;
    const int py = pix >> 3, px = pix & 7;
    const _Float16* xbase = &xt[slot * 776];

    float acc[4][8];
#pragma unroll
    for (int s = 0; s < 4; ++s)
#pragma unroll
      for (int j = 0; j < 8; ++j) acc[s][j] = 0.f;

#pragma unroll
    for (int ki = 0; ki < 5; ++ki) {
#pragma unroll
      for (int kj = 0; kj < 5; ++kj) {
        int tap = ki * 5 + kj;
        f16x4 wh = *(const f16x4*)&smw[tap * 128 + pix * 4];
        f16x8 xh = *(const f16x8*)&xbase[(py + ki) * 96 + (px + kj) * 8];
        float wf0 = (float)wh[0], wf1 = (float)wh[1], wf2 = (float)wh[2], wf3 = (float)wh[3];
#pragma unroll
        for (int j = 0; j < 8; ++j) {
          float xv = (float)xh[j];
          acc[0][j] = fmaf(wf0, xv, acc[0][j]);
          acc[1][j] = fmaf(wf1, xv, acc[1][j]);
          acc[2][j] = fmaf(wf2, xv, acc[2][j]);
          acc[3][j] = fmaf(wf3, xv, acc[3][j]);
        }
      }
    }
    int y0o = 2 * (ty0 + py), x0o = 2 * (tx0 + px);
#pragma unroll
    for (int j = 0; j < 8; ++j) {
      int c = slot * 8 + j;
      float* op = out + ((size_t)(b * 128 + c) * 128 + y0o) * 128 + x0o;
      float2 v0 = {acc[0][j], acc[1][j]};
      float2 v1 = {acc[2][j], acc[3][j]};
      *(float2*)op = v0;
      *(float2*)(op + 128) = v1;
    }
  }
}

// ---------------------------------------------------------------------------
extern "C" void kernel_launch(void* const* d_in, const int* in_sizes, int n_in,
                              void* d_out, int out_size, void* d_ws, size_t ws_size,
                              hipStream_t stream) {
  const float* X     = (const float*)d_in[0];
  const float* w3    = (const float*)d_in[1];
  const float* b3    = (const float*)d_in[2];
  const float* w5    = (const float*)d_in[3];
  const float* b5    = (const float*)d_in[4];
  const float* wa1   = (const float*)d_in[5];
  const float* ba1   = (const float*)d_in[6];
  const float* wa2   = (const float*)d_in[7];
  const float* ba2   = (const float*)d_in[8];
  const float* wedge = (const float*)d_in[9];
  const float* wenc  = (const float*)d_in[10];
  char* wsb = (char*)d_ws;  // ~5.34 MB
  float* out = (float*)d_out;

  _Float16* xpad8  = (_Float16*)(wsb + XPAD8_B);
  f16x8*    wfc    = (f16x8*)(wsb + WFC_B);
  f16x8*    wfe    = (f16x8*)(wsb + WFE_B);
  _Float16* wfeatp = (_Float16*)(wsb + WFEATP_B);
  _Float16* wpadp  = (_Float16*)(wsb + WPADP_B);
  float*    bcomb  = (float*)(wsb + BCOMB_B);
  float*    avg    = (float*)(wsb + AVG_B);

  prep_kernel<<<612, 256, 0, stream>>>(X, w3, b3, w5, b5, wenc, wsb);
  convw_kernel<<<dim3(8, 16, 4), 256, 0, stream>>>(xpad8, wfc, bcomb, wfeatp, avg);
  edge_kernel<<<64, 256, 0, stream>>>(wedge, wa1, ba1, wa2, ba2, avg, wfeatp, wpadp);
  enccarafe_kernel<<<dim3(8, 16, 2), 512, 0, stream>>>(wpadp, wfe, xpad8, out);
}

// Round 7
// 47.650 us; speedup vs baseline: 5.4614x; 1.0832x over previous
//
#include <hip/hip_runtime.h>
#include <math.h>

typedef __attribute__((ext_vector_type(2))) _Float16 f16x2;
typedef __attribute__((ext_vector_type(4))) _Float16 f16x4;
typedef __attribute__((ext_vector_type(8))) _Float16 f16x8;
typedef __attribute__((ext_vector_type(4))) float f32x4;

#if __has_builtin(__builtin_amdgcn_fdot2)
#define FDOT2(a, b, c) __builtin_amdgcn_fdot2((a), (b), (c), false)
#else
static __device__ __forceinline__ float FDOT2(f16x2 a, f16x2 b, float c) {
  return c + (float)a[0] * (float)b[0] + (float)a[1] * (float)b[1];
}
#endif

// Workspace byte offsets
#define XPAD8_B  0           // [2][16 gg][68 y][72 x][8 ci] f16 (data at y+2,x+2)
#define WFC_B    2506752     // convw B-frags [25 t][4 cc][4 ntg][64 l] f16x8
#define WFE_B    2916352     // enc  B-frags [9 t][2 cc][7 nt][64 l] f16x8
#define WFEATP_B 3045376     // [2][8 gg][66][68][8] f16 pre-edge W (data at +1,+1)
#define WEDGET_B 4194304     // [9 k][8 gg] f16x8 (j fastest) depthwise weights
#define BCOMB_B  4195456     // [64] f32
#define AVG_B    4195712     // [128] f32 (seeded with bias)
// total ~4.2 MB

// ---------------------------------------------------------------------------
// prep: Xpad8, MFMA B-frag packs (K=32), wfeatp border zeros, wedgeT, bias.
// ---------------------------------------------------------------------------
__global__ __launch_bounds__(256) void prep_kernel(
    const float* __restrict__ X,
    const float* __restrict__ w3, const float* __restrict__ b3,
    const float* __restrict__ w5, const float* __restrict__ b5,
    const float* __restrict__ wedge, const float* __restrict__ wenc,
    char* __restrict__ wsb) {
  int idx = blockIdx.x * 256 + threadIdx.x;
  if (idx < 156672) {  // Xpad8
    int x = idx % 72;
    int t = idx / 72;
    int y = t % 68;
    int t2 = t / 68;
    int gg = t2 & 15, b = t2 >> 4;
    int yy = y - 2, xx = x - 2;
    bool ok = (yy >= 0 && yy < 64 && xx >= 0 && xx < 64);
    f16x8 h;
#pragma unroll
    for (int j = 0; j < 8; ++j) {
      float v = ok ? X[((b * 128 + gg * 8 + j) << 12) + yy * 64 + xx] : 0.f;
      h[j] = (_Float16)v;
    }
    ((f16x8*)(wsb + XPAD8_B))[idx] = h;
  }
  if (idx < 25600) {  // convw frags: ((t*4+cc)*4+ntg)*64 + l
    int l = idx & 63;
    int q = idx >> 6;
    int ntg = q & 3;
    int q2 = q >> 2;
    int cc = q2 & 3;
    int t = q2 >> 2;
    int ky = t / 5, kx = t % 5;
    int oc = ntg * 16 + (l & 15);
    int ci0 = cc * 32 + (l >> 4) * 8;
    f16x8 h;
#pragma unroll
    for (int i = 0; i < 8; ++i) {
      int ci = ci0 + i;
      float v = w5[(oc * 128 + ci) * 25 + t];
      if (ky >= 1 && ky <= 3 && kx >= 1 && kx <= 3)
        v += w3[(oc * 128 + ci) * 9 + (ky - 1) * 3 + (kx - 1)];
      h[i] = (_Float16)v;
    }
    ((f16x8*)(wsb + WFC_B))[idx] = h;
  }
  if (idx < 8064) {  // enc frags: ((t*2+cc)*7+nt)*64 + l
    int l = idx & 63;
    int q = idx >> 6;
    int nt = q % 7;
    int q2 = q / 7;
    int cc = q2 & 1;
    int t = q2 >> 1;
    int oc = nt * 16 + (l & 15);
    int ci0 = cc * 32 + (l >> 4) * 8;
    f16x8 h;
#pragma unroll
    for (int i = 0; i < 8; ++i) {
      float v = (oc < 100) ? wenc[(oc * 64 + ci0 + i) * 9 + t] : 0.f;
      h[i] = (_Float16)v;
    }
    ((f16x8*)(wsb + WFE_B))[idx] = h;
  }
  if (idx < 6272) {  // wfeatp border zeros: 16 planes x 392 positions
    int plane = idx / 392, p = idx % 392;
    int r, c;
    if (p < 136) {
      r = (p >= 68) ? 65 : 0;
      c = p % 68;
    } else {
      int q = p - 136;
      r = 1 + (q >> 2);
      int cm = q & 3;
      c = (cm == 0) ? 0 : (64 + cm);
    }
    f16x8 z = {(_Float16)0.f, (_Float16)0.f, (_Float16)0.f, (_Float16)0.f,
               (_Float16)0.f, (_Float16)0.f, (_Float16)0.f, (_Float16)0.f};
    *(f16x8*)((_Float16*)(wsb + WFEATP_B) + ((size_t)(plane * 66 + r) * 68 + c) * 8) = z;
  }
  if (idx < 72) {  // wedgeT [k][gg] f16x8 over j
    int k = idx >> 3, gg = idx & 7;
    f16x8 h;
#pragma unroll
    for (int j = 0; j < 8; ++j) h[j] = (_Float16)wedge[(gg * 8 + j) * 9 + k];
    ((f16x8*)(wsb + WEDGET_B))[idx] = h;
  }
  if (idx < 64) ((float*)(wsb + BCOMB_B))[idx] = b3[idx] + b5[idx];
  if (idx < 128) ((float*)(wsb + AVG_B))[idx] = b3[idx & 63] + b5[idx & 63];
}

// ---------------------------------------------------------------------------
// convw: 5x5 conv, mfma 16x16x32, fused mean. Grid (8,8,8): z = b*4 + ntg.
// 256 thr = 4 waves (pixel 16-groups of an 8x8 tile); 16 oc per block.
// LDS: [16 gg][12 r][12 c][8] f16, gg-stride 1160.
// ---------------------------------------------------------------------------
__global__ __launch_bounds__(256) void convw_kernel(
    const _Float16* __restrict__ xpad8, const f16x8* __restrict__ wfc,
    const float* __restrict__ bcomb, _Float16* __restrict__ wfeatp,
    float* __restrict__ avg) {
  __shared__ __attribute__((aligned(16))) _Float16 xs[18560];
  __shared__ float red[64];
  const int tid = threadIdx.x;
  const int z = blockIdx.z;
  const int b = z >> 2, ntg = z & 3;
  const int tx0 = blockIdx.x * 8, ty0 = blockIdx.y * 8;

  for (int u = tid; u < 2304; u += 256) {
    int gg = u / 144;
    int rem = u - gg * 144;
    int r = rem / 12, c = rem - r * 12;
    f16x8 v = *(const f16x8*)&xpad8[((size_t)((b * 16 + gg) * 68 + ty0 + r) * 72 + tx0 + c) * 8];
    *(f16x8*)&xs[gg * 1160 + r * 96 + c * 8] = v;
  }
  __syncthreads();

  const int w = __builtin_amdgcn_readfirstlane(tid >> 6);
  const int l = tid & 63;
  const int lm = l & 15, lg = l >> 4;
  const int p = w * 16 + lm;
  const int abase = (p >> 3) * 96 + (p & 7) * 8;

  f32x4 accA = {0.f, 0.f, 0.f, 0.f}, accB = {0.f, 0.f, 0.f, 0.f};
  for (int dy = 0; dy < 5; ++dy) {
    for (int dx = 0; dx < 5; ++dx) {
      const int t = dy * 5 + dx;
      const int toff = abase + dy * 96 + dx * 8;
      const f16x8* wt = wfc + (t * 16 + ntg) * 64 + l;  // + cc*256
#pragma unroll
      for (int cc = 0; cc < 4; ++cc) {
        f16x8 a = *(const f16x8*)&xs[(cc * 4 + lg) * 1160 + toff];
        f16x8 bb = wt[cc * 256];
        if (cc & 1)
          accB = __builtin_amdgcn_mfma_f32_16x16x32_f16(a, bb, accB, 0, 0, 0);
        else
          accA = __builtin_amdgcn_mfma_f32_16x16x32_f16(a, bb, accA, 0, 0, 0);
      }
    }
  }
  f32x4 acc = accA + accB;

  float s = acc[0] + acc[1] + acc[2] + acc[3];
  s += __shfl_xor(s, 16);
  s += __shfl_xor(s, 32);
  const float bias = bcomb[ntg * 16 + lm];
  __syncthreads();  // xs free: repack [64 pd][16 oc] stride 24
#pragma unroll
  for (int r = 0; r < 4; ++r) {
    int pd = w * 16 + lg * 4 + r;
    xs[pd * 24 + lm] = (_Float16)(acc[r] + bias);
  }
  if (l < 16) red[w * 16 + lm] = s;
  __syncthreads();
  if (tid < 128) {
    int g2 = tid >> 6, pd = tid & 63;
    f16x8 v = *(const f16x8*)&xs[pd * 24 + g2 * 8];
    int gy = ty0 + (pd >> 3), gx = tx0 + (pd & 7);
    *(f16x8*)&wfeatp[((size_t)((b * 8 + ntg * 2 + g2) * 66 + 1 + gy) * 68 + 1 + gx) * 8] = v;
  }
  if (tid < 16) {
    float tot = red[tid] + red[16 + tid] + red[32 + tid] + red[48 + tid];
    atomicAdd(&avg[b * 64 + ntg * 16 + tid], tot * (1.f / 4096.f));
  }
}

// ---------------------------------------------------------------------------
// enccarafe: fused gate + edge + enc MFMA + softmax + carafe (fdot2).
// Grid (8,16,2): z = b. 512 thr. Tile: 8 wide x 4 high low-res pixels.
// smem: xt[16][8r][13c][8] | xsv[8][6r][10c][8] | {ts[8][8r][12c][8] / sml+smw2}
// ---------------------------------------------------------------------------
#define SM_XT  0       // 16*840 f16 = 26880 B
#define SM_XSV 26880   // 8*488 f16 = 7808 B
#define SM_TS  34688   // 8*776 f16 = 12416 B (aliased with sml/smw2)
#define SM_SML 34688   // 32*116 f32 = 14848 B
#define SM_SMW 49536   // 15*32*4 f16x2 = 7680 B
#define SM_TOT 57216

__global__ __launch_bounds__(512) void enccarafe_kernel(
    const _Float16* __restrict__ wfeatp, const f16x8* __restrict__ wfe,
    const _Float16* __restrict__ xpad8, const f16x8* __restrict__ wedgeT,
    const float* __restrict__ wa1, const float* __restrict__ ba1,
    const float* __restrict__ wa2, const float* __restrict__ ba2,
    const float* __restrict__ avg, float* __restrict__ out) {
  __shared__ __attribute__((aligned(16))) char smem[SM_TOT];
  __shared__ f16x8 wedt[72];
  __shared__ float tlat[8];
  __shared__ float gsh[64];
  _Float16* xt = (_Float16*)(smem + SM_XT);
  _Float16* xsv = (_Float16*)(smem + SM_XSV);
  _Float16* ts = (_Float16*)(smem + SM_TS);
  float* sml = (float*)(smem + SM_SML);
  f16x2* smw2 = (f16x2*)(smem + SM_SMW);

  const int tid = threadIdx.x;
  const int b = blockIdx.z;
  const int tx0 = blockIdx.x * 8, ty0 = blockIdx.y * 4;

  // --- stage X tile (carafe), W halo tile (edge), wedge, latent ---
  for (int u = tid; u < 1664; u += 512) {
    int gg = u / 104;
    int rem = u - gg * 104;
    int r = rem / 13, c = rem - r * 13;
    f16x8 v = *(const f16x8*)&xpad8[((size_t)((b * 16 + gg) * 68 + ty0 + r) * 72 + tx0 + c) * 8];
    *(f16x8*)&xt[gg * 840 + r * 104 + c * 8] = v;
  }
  for (int u = tid; u < 768; u += 512) {
    int gg = u / 96;
    int rem = u - gg * 96;
    int r = rem / 12, c = rem - r * 12;
    int pr = ty0 - 1 + r, pc = tx0 - 1 + c;
    f16x8 v = {(_Float16)0.f, (_Float16)0.f, (_Float16)0.f, (_Float16)0.f,
               (_Float16)0.f, (_Float16)0.f, (_Float16)0.f, (_Float16)0.f};
    if (pr >= 0 && pr < 66 && pc >= 0 && pc < 68)
      v = *(const f16x8*)&wfeatp[((size_t)((b * 8 + gg) * 66 + pr) * 68 + pc) * 8];
    *(f16x8*)&ts[gg * 776 + r * 96 + c * 8] = v;
  }
  if (tid < 72) wedt[tid] = wedgeT[tid];
  if (tid < 8) {
    float s = ba1[tid];
    for (int i = 0; i < 64; ++i) s += wa1[tid * 64 + i] * avg[b * 64 + i];
    tlat[tid] = s;
  }
  __syncthreads();
  if (tid < 64) {
    float s = ba2[tid];
#pragma unroll
    for (int j = 0; j < 8; ++j) s += wa2[tid * 8 + j] * tlat[j];
    gsh[tid] = 1.f / (1.f + expf(-s));
  }
  __syncthreads();

  // --- edge: V = W*gate + depthwise3x3(W), into xsv (6r x 10c x 64ch) ---
  for (int u = tid; u < 480; u += 512) {
    int gg = u / 60;
    int rem = u - gg * 60;
    int r6 = rem / 10, c10 = rem - r6 * 10;
    int vy = ty0 - 1 + r6, vx = tx0 - 1 + c10;
    f16x8 res = {(_Float16)0.f, (_Float16)0.f, (_Float16)0.f, (_Float16)0.f,
                 (_Float16)0.f, (_Float16)0.f, (_Float16)0.f, (_Float16)0.f};
    if (vy >= 0 && vy < 64 && vx >= 0 && vx < 64) {
      float vout[8];
      f16x8 ctr = *(const f16x8*)&ts[gg * 776 + (r6 + 1) * 96 + (c10 + 1) * 8];
#pragma unroll
      for (int j = 0; j < 8; ++j) vout[j] = (float)ctr[j] * gsh[gg * 8 + j];
#pragma unroll
      for (int ky = 0; ky < 3; ++ky) {
#pragma unroll
        for (int kx = 0; kx < 3; ++kx) {
          int k = ky * 3 + kx;
          f16x8 tv = *(const f16x8*)&ts[gg * 776 + (r6 + ky) * 96 + (c10 + kx) * 8];
          f16x8 wv = wedt[k * 8 + gg];
#pragma unroll
          for (int j = 0; j < 8; ++j) vout[j] = fmaf((float)wv[j], (float)tv[j], vout[j]);
        }
      }
#pragma unroll
      for (int j = 0; j < 8; ++j) res[j] = (_Float16)vout[j];
    }
    *(f16x8*)&xsv[gg * 488 + r6 * 80 + c10 * 8] = res;
  }
  __syncthreads();

  // --- enc MFMA: V (6x10 halo) -> 112 logits per pixel, into sml ---
  {
    const int w = __builtin_amdgcn_readfirstlane(tid >> 6);
    const int l = tid & 63;
    const int pg = w & 1, hs = w >> 1;
    const int lm = l & 15, lg = l >> 4;
    const int p = pg * 16 + lm;
    const int abase = (p >> 3) * 80 + (p & 7) * 8;
    const int nt0 = hs * 2;
    const int ncnt = (hs == 3) ? 1 : 2;

    f32x4 a0 = {0.f, 0.f, 0.f, 0.f}, a1 = {0.f, 0.f, 0.f, 0.f};
    for (int dy = 0; dy < 3; ++dy) {
      for (int dx = 0; dx < 3; ++dx) {
        const int t = dy * 3 + dx;
        const int toff = abase + dy * 80 + dx * 8;
#pragma unroll
        for (int cc = 0; cc < 2; ++cc) {
          f16x8 a = *(const f16x8*)&xsv[(cc * 4 + lg) * 488 + toff];
          f16x8 b0 = wfe[((t * 2 + cc) * 7 + nt0) * 64 + l];
          a0 = __builtin_amdgcn_mfma_f32_16x16x32_f16(a, b0, a0, 0, 0, 0);
          if (ncnt == 2) {
            f16x8 b1 = wfe[((t * 2 + cc) * 7 + nt0 + 1) * 64 + l];
            a1 = __builtin_amdgcn_mfma_f32_16x16x32_f16(a, b1, a1, 0, 0, 0);
          }
        }
      }
    }
#pragma unroll
    for (int r = 0; r < 4; ++r) {
      int pd = pg * 16 + 4 * lg + r;
      sml[pd * 116 + nt0 * 16 + lm] = a0[r];
      if (ncnt == 2) sml[pd * 116 + (nt0 + 1) * 16 + lm] = a1[r];
    }
  }
  __syncthreads();

  // --- softmax over 25 taps x 4 subpix -> paired f16x2 weights ---
  if (tid < 128) {
    int pix = tid >> 2, sub = tid & 3;
    float lv[25];
    float m = -1e30f;
#pragma unroll
    for (int k = 0; k < 25; ++k) {
      lv[k] = sml[pix * 116 + k * 4 + sub];
      m = fmaxf(m, lv[k]);
    }
    float s = 0.f;
#pragma unroll
    for (int k = 0; k < 25; ++k) {
      lv[k] = __expf(lv[k] - m);
      s += lv[k];
    }
    float inv = 1.f / s;
#pragma unroll
    for (int ki = 0; ki < 5; ++ki) {
#pragma unroll
      for (int pr = 0; pr < 3; ++pr) {
        float wlo = lv[ki * 5 + 2 * pr] * inv;
        float whi = (2 * pr + 1 < 5) ? lv[ki * 5 + 2 * pr + 1] * inv : 0.f;
        f16x2 pk = {(_Float16)wlo, (_Float16)whi};
        smw2[((ki * 3 + pr) * 32 + pix) * 4 + sub] = pk;
      }
    }
  }
  __syncthreads();

  // --- carafe gather via fdot2 over tap pairs ---
  {
    const int slot = tid >> 5, pix = tid & 31;
    const int py = pix >> 3, px = pix & 7;
    const _Float16* xb = xt + slot * 840;

    float acc[4][8];
#pragma unroll
    for (int s = 0; s < 4; ++s)
#pragma unroll
      for (int j = 0; j < 8; ++j) acc[s][j] = 0.f;

    union U8 { f16x8 v; unsigned int u[4]; };
#pragma unroll
    for (int ki = 0; ki < 5; ++ki) {
      const _Float16* row = xb + (py + ki) * 104 + px * 8;
      U8 C[6];
#pragma unroll
      for (int c = 0; c < 6; ++c) C[c].v = *(const f16x8*)(row + c * 8);
#pragma unroll
      for (int pr = 0; pr < 3; ++pr) {
        const f16x2* wp = &smw2[((ki * 3 + pr) * 32 + pix) * 4];
        f16x2 w0 = wp[0], w1 = wp[1], w2 = wp[2], w3 = wp[3];
        const U8& A = C[2 * pr];
        const U8& B = C[2 * pr + 1];
#pragma unroll
        for (int k = 0; k < 4; ++k) {
          unsigned int lo = __builtin_amdgcn_perm(B.u[k], A.u[k], 0x05040100u);
          unsigned int hi = __builtin_amdgcn_perm(B.u[k], A.u[k], 0x07060302u);
          f16x2 xlo = __builtin_bit_cast(f16x2, lo);
          f16x2 xhi = __builtin_bit_cast(f16x2, hi);
          acc[0][2 * k] = FDOT2(w0, xlo, acc[0][2 * k]);
          acc[1][2 * k] = FDOT2(w1, xlo, acc[1][2 * k]);
          acc[2][2 * k] = FDOT2(w2, xlo, acc[2][2 * k]);
          acc[3][2 * k] = FDOT2(w3, xlo, acc[3][2 * k]);
          acc[0][2 * k + 1] = FDOT2(w0, xhi, acc[0][2 * k + 1]);
          acc[1][2 * k + 1] = FDOT2(w1, xhi, acc[1][2 * k + 1]);
          acc[2][2 * k + 1] = FDOT2(w2, xhi, acc[2][2 * k + 1]);
          acc[3][2 * k + 1] = FDOT2(w3, xhi, acc[3][2 * k + 1]);
        }
      }
    }
    int y0o = 2 * (ty0 + py), x0o = 2 * (tx0 + px);
#pragma unroll
    for (int j = 0; j < 8; ++j) {
      int c = slot * 8 + j;
      float* op = out + ((size_t)(b * 128 + c) * 128 + y0o) * 128 + x0o;
      float2 v0 = {acc[0][j], acc[1][j]};
      float2 v1 = {acc[2][j], acc[3][j]};
      *(float2*)op = v0;
      *(float2*)(op + 128) = v1;
    }
  }
}

// ---------------------------------------------------------------------------
extern "C" void kernel_launch(void* const* d_in, const int* in_sizes, int n_in,
                              void* d_out, int out_size, void* d_ws, size_t ws_size,
                              hipStream_t stream) {
  const float* X     = (const float*)d_in[0];
  const float* w3    = (const float*)d_in[1];
  const float* b3    = (const float*)d_in[2];
  const float* w5    = (const float*)d_in[3];
  const float* b5    = (const float*)d_in[4];
  const float* wa1   = (const float*)d_in[5];
  const float* ba1   = (const float*)d_in[6];
  const float* wa2   = (const float*)d_in[7];
  const float* ba2   = (const float*)d_in[8];
  const float* wedge = (const float*)d_in[9];
  const float* wenc  = (const float*)d_in[10];
  char* wsb = (char*)d_ws;  // ~4.2 MB
  float* out = (float*)d_out;

  _Float16* xpad8  = (_Float16*)(wsb + XPAD8_B);
  f16x8*    wfc    = (f16x8*)(wsb + WFC_B);
  f16x8*    wfe    = (f16x8*)(wsb + WFE_B);
  _Float16* wfeatp = (_Float16*)(wsb + WFEATP_B);
  f16x8*    wedgeT = (f16x8*)(wsb + WEDGET_B);
  float*    bcomb  = (float*)(wsb + BCOMB_B);
  float*    avg    = (float*)(wsb + AVG_B);

  prep_kernel<<<612, 256, 0, stream>>>(X, w3, b3, w5, b5, wedge, wenc, wsb);
  convw_kernel<<<dim3(8, 8, 8), 256, 0, stream>>>(xpad8, wfc, bcomb, wfeatp, avg);
  enccarafe_kernel<<<dim3(8, 16, 2), 512, 0, stream>>>(
      wfeatp, wfe, xpad8, wedgeT, wa1, ba1, wa2, ba2, avg, out);
}